// Round 3
// baseline (494.415 us; speedup 1.0000x reference)
//
#include <hip/hip_runtime.h>
#include <hip/hip_bf16.h>
#include <cstdint>
#include <cstddef>

// ---------- types ----------
typedef __attribute__((ext_vector_type(8))) __bf16 bf16x8;
typedef __attribute__((ext_vector_type(4))) float f32x4;
typedef __attribute__((ext_vector_type(4))) unsigned short u16x4;

#define DEVINL static __device__ __forceinline__

DEVINL unsigned short f2bf(float x) {
  union { float f; unsigned u; } un; un.f = x;
  unsigned r = un.u + 0x7fffu + ((un.u >> 16) & 1u);
  return (unsigned short)(r >> 16);
}

DEVINL void gload16(const void* g, void* l) {
  __builtin_amdgcn_global_load_lds(
      (__attribute__((address_space(1))) void*)(void*)(uintptr_t)(const void*)g,
      (__attribute__((address_space(3))) void*)l, 16, 0, 0);
}

// ---------- fused: row/col sums of tilde + convert tilde -> bf16 ----------
// 1024 blocks x 8 rows each (4 blocks/CU, 16 waves/CU); shuffles+atomics deferred
// to block tail so the load stream stays pipelined.
__global__ __launch_bounds__(256, 4) void sums_convert(const float* __restrict__ tilde,
                                                       float* __restrict__ D1,
                                                       float* __restrict__ D2,
                                                       u16x4* __restrict__ Tbf) {
  const int t = threadIdx.x;
  float ca[8][4];
#pragma unroll
  for (int i = 0; i < 8; ++i)
#pragma unroll
    for (int j = 0; j < 4; ++j) ca[i][j] = 0.f;
  float rs[8];
#pragma unroll
  for (int r = 0; r < 8; ++r) rs[r] = 0.f;

  const int base_row = blockIdx.x * 8;
#pragma unroll
  for (int r = 0; r < 8; ++r) {
    const size_t rowoff = (size_t)(base_row + r) * 2048;  // float4 units
    const float4* rp = (const float4*)tilde + rowoff;
    u16x4* op = Tbf + rowoff;
#pragma unroll
    for (int i = 0; i < 8; ++i) {
      float4 v = rp[t + i * 256];
      ca[i][0] += v.x; ca[i][1] += v.y; ca[i][2] += v.z; ca[i][3] += v.w;
      rs[r] += (v.x + v.y) + (v.z + v.w);
      u16x4 o;
      o[0] = f2bf(v.x); o[1] = f2bf(v.y); o[2] = f2bf(v.z); o[3] = f2bf(v.w);
      op[t + i * 256] = o;
    }
  }
  // deferred row-sum reductions
#pragma unroll
  for (int r = 0; r < 8; ++r) {
#pragma unroll
    for (int off = 32; off > 0; off >>= 1) rs[r] += __shfl_down(rs[r], off, 64);
  }
  if ((t & 63) == 0) {
#pragma unroll
    for (int r = 0; r < 8; ++r) atomicAdd(&D2[base_row + r], rs[r]);
  }
  // deferred column-partial atomics
#pragma unroll
  for (int i = 0; i < 8; ++i)
#pragma unroll
    for (int j = 0; j < 4; ++j)
      atomicAdd(&D1[(t + i * 256) * 4 + j], ca[i][j]);
}

// ---------- s[j] = sqrt(D1[j]*D2[j]) ----------
__global__ __launch_bounds__(256) void colscale_kernel(const float* __restrict__ D1,
                                                       const float* __restrict__ D2,
                                                       float* __restrict__ s) {
  int i = blockIdx.x * 256 + threadIdx.x;
  s[i] = sqrtf(D1[i] * D2[i]);
}

// ---------- fp32 -> bf16 convert ----------
__global__ __launch_bounds__(256) void convert_bf16(const float4* __restrict__ in,
                                                    u16x4* __restrict__ out, int n4) {
  const int stride = gridDim.x * 256;
  for (int i = blockIdx.x * 256 + threadIdx.x; i < n4; i += stride) {
    float4 v = in[i];
    u16x4 o;
    o[0] = f2bf(v.x); o[1] = f2bf(v.y); o[2] = f2bf(v.z); o[3] = f2bf(v.w);
    out[i] = o;
  }
}

// ---------- transpose + convert: out[c][r] = bf16(in[r][c]) ----------
__global__ __launch_bounds__(256) void transpose_cvt(const float* __restrict__ in,
                                                     unsigned short* __restrict__ out,
                                                     int R, int C) {
  int o = blockIdx.x * 256 + threadIdx.x;
  if (o >= R * C) return;
  int c = o / R, r = o - c * R;
  out[o] = f2bf(in[(size_t)r * C + c]);
}

// ---------- tiled MFMA GEMM: C[M,N] = A[M,K] @ B[K,N], BT given as [N][K] ----------
// EPI: 1 = bf16 out + relu; 2 = f32 partial out (split-K); 3 = bf16 out, (acc+bias[row])*cs[col]
template <int BM, int BN, int EPI>
__global__ __launch_bounds__(256) void gemm_bt(
    const unsigned short* __restrict__ A,   // [M][K] bf16 row-major
    const unsigned short* __restrict__ BT,  // [N][K] bf16 row-major
    void* __restrict__ C,
    const float* __restrict__ bias,
    const float* __restrict__ cs,
    int M, int N, int K, int kChunk, int ldc) {
  constexpr int WTM = BM / 2, WTN = BN / 2;
  constexpr int MR = WTM / 16, NR = WTN / 16;
  constexpr int AIT = BM * 4 / 256;
  constexpr int BIT = BN * 4 / 256;

  __shared__ unsigned short As[BM * 32];
  __shared__ unsigned short Bs[BN * 32];

  const int t = threadIdx.x;
  const int lane = t & 63, wave = t >> 6;
  const int wr = wave >> 1, wc = wave & 1;
  const int bm = blockIdx.x, bn = blockIdx.y, bz = blockIdx.z;
  const int row0 = bm * BM, col0 = bn * BN;
  const int kbeg = bz * kChunk, kend = kbeg + kChunk;
  const int lrow = lane & 15;
  const int lk = (lane >> 4) * 8;

  f32x4 acc[MR][NR];
#pragma unroll
  for (int m = 0; m < MR; ++m)
#pragma unroll
    for (int n = 0; n < NR; ++n) acc[m][n] = (f32x4){0.f, 0.f, 0.f, 0.f};

  for (int k0 = kbeg; k0 < kend; k0 += 32) {
#pragma unroll
    for (int i = 0; i < AIT; ++i) {
      int flat = i * 256 + t;
      int r = flat >> 2, ko = (flat & 3) * 8;
      gload16(A + (size_t)(row0 + r) * K + k0 + ko, As + (size_t)flat * 8);
    }
#pragma unroll
    for (int i = 0; i < BIT; ++i) {
      int flat = i * 256 + t;
      int r = flat >> 2, ko = (flat & 3) * 8;
      gload16(BT + (size_t)(col0 + r) * K + k0 + ko, Bs + (size_t)flat * 8);
    }
    __syncthreads();

    bf16x8 af[MR], bfr[NR];
#pragma unroll
    for (int m = 0; m < MR; ++m)
      af[m] = *(const bf16x8*)&As[(wr * WTM + m * 16 + lrow) * 32 + lk];
#pragma unroll
    for (int n = 0; n < NR; ++n)
      bfr[n] = *(const bf16x8*)&Bs[(wc * WTN + n * 16 + lrow) * 32 + lk];
#pragma unroll
    for (int m = 0; m < MR; ++m)
#pragma unroll
      for (int n = 0; n < NR; ++n)
        acc[m][n] = __builtin_amdgcn_mfma_f32_16x16x32_bf16(af[m], bfr[n], acc[m][n], 0, 0, 0);
    __syncthreads();
  }

  const int r0 = row0 + wr * WTM, c0 = col0 + wc * WTN;
  if constexpr (EPI == 2) {
    float* Cf = (float*)C + (size_t)bz * M * ldc;
#pragma unroll
    for (int m = 0; m < MR; ++m)
#pragma unroll
      for (int n = 0; n < NR; ++n)
#pragma unroll
        for (int j = 0; j < 4; ++j) {
          int row = r0 + m * 16 + (lane >> 4) * 4 + j;
          int col = c0 + n * 16 + lrow;
          Cf[(size_t)row * ldc + col] = acc[m][n][j];
        }
  } else {
    unsigned short* Cb = (unsigned short*)C;
#pragma unroll
    for (int m = 0; m < MR; ++m)
#pragma unroll
      for (int n = 0; n < NR; ++n)
#pragma unroll
        for (int j = 0; j < 4; ++j) {
          int row = r0 + m * 16 + (lane >> 4) * 4 + j;
          int col = c0 + n * 16 + lrow;
          float v = acc[m][n][j];
          if constexpr (EPI == 1) v = v > 0.f ? v : 0.f;
          if constexpr (EPI == 3) v = (v + bias[row]) * cs[col];
          Cb[(size_t)row * ldc + col] = f2bf(v);
        }
  }
}

// ---------- reduce split-K partials -> relu -> bf16 ----------
__global__ __launch_bounds__(256) void reduce_relu_bf16(const float4* __restrict__ part,
                                                        u16x4* __restrict__ out,
                                                        int total4, int splits) {
  const int stride = gridDim.x * 256;
  for (int i = blockIdx.x * 256 + threadIdx.x; i < total4; i += stride) {
    float4 s = part[i];
    for (int z = 1; z < splits; ++z) {
      float4 v = part[(size_t)z * total4 + i];
      s.x += v.x; s.y += v.y; s.z += v.z; s.w += v.w;
    }
    u16x4 o;
    o[0] = f2bf(s.x > 0.f ? s.x : 0.f);
    o[1] = f2bf(s.y > 0.f ? s.y : 0.f);
    o[2] = f2bf(s.z > 0.f ? s.z : 0.f);
    o[3] = f2bf(s.w > 0.f ? s.w : 0.f);
    out[i] = o;
  }
}

// ---------- reduce split-K partials -> f32 ----------
__global__ __launch_bounds__(256) void reduce_f32(const float4* __restrict__ part,
                                                  float4* __restrict__ out,
                                                  int total4, int splits) {
  const int stride = gridDim.x * 256;
  for (int i = blockIdx.x * 256 + threadIdx.x; i < total4; i += stride) {
    float4 s = part[i];
    for (int z = 1; z < splits; ++z) {
      float4 v = part[(size_t)z * total4 + i];
      s.x += v.x; s.y += v.y; s.z += v.z; s.w += v.w;
    }
    out[i] = s;
  }
}

// ---------- launch ----------
extern "C" void kernel_launch(void* const* d_in, const int* in_sizes, int n_in,
                              void* d_out, int out_size, void* d_ws, size_t ws_size,
                              hipStream_t stream) {
  const float* X     = (const float*)d_in[0];
  const float* tilde = (const float*)d_in[1];
  const float* W1    = (const float*)d_in[2];
  const float* b1    = (const float*)d_in[3];
  const float* W2    = (const float*)d_in[4];
  const float* b2    = (const float*)d_in[5];
  float* out = (float*)d_out;

  constexpr int N = 8192, F = 1024, H = 512, Cc = 64;

  char* ws = (char*)d_ws;
  size_t off = 0;
  auto alloc = [&](size_t bytes) {
    char* p = ws + off;
    off += (bytes + 255) & ~(size_t)255;
    return p;
  };
  // persistent-ish region
  unsigned short* Tbf  = (unsigned short*)alloc((size_t)N * N * 2);   // 128 MB (live thru gemm4)
  unsigned short* XW1T = (unsigned short*)alloc((size_t)H * N * 2);   // 8 MB  (dead after gemm2)
  unsigned short* hbuf = (unsigned short*)alloc((size_t)N * H * 2);   // 8 MB  (dead after gemm3)
  unsigned short* ZT   = (unsigned short*)alloc((size_t)Cc * N * 2);  // 1 MB  (dead after gemm4)
  unsigned short* W2T  = (unsigned short*)alloc((size_t)Cc * H * 2);  // 64 KB
  float* D1 = (float*)alloc(N * 4);
  float* D2 = (float*)alloc(N * 4);
  float* sv = (float*)alloc(N * 4);
  // scratch zone (serial reuse): [Xbf 16MB | W1T 1MB] -> [part2 64MB] -> [part4 16MB]
  const size_t scratch_base = off;
  unsigned short* Xbf = (unsigned short*)(ws + scratch_base);                      // 16 MB
  unsigned short* W1T = (unsigned short*)(ws + scratch_base + (size_t)N * F * 2);  // 1 MB
  float* part2 = (float*)(ws + scratch_base);  // 4 * 8192*512*4 = 64 MB
  float* part4 = (float*)(ws + scratch_base);  // 8 * 8192*64*4  = 16 MB

  const size_t need_split = scratch_base + (size_t)4 * N * H * 4;     // ~209 MB
  const bool splitk2 = ws_size >= need_split;

  hipMemsetAsync(D1, 0, N * 4, stream);
  hipMemsetAsync(D2, 0, N * 4, stream);

  // fused sums + tilde->bf16 (A never materialized; scale folded into later epilogues)
  sums_convert<<<1024, 256, 0, stream>>>(tilde, D1, D2, (u16x4*)Tbf);
  colscale_kernel<<<N / 256, 256, 0, stream>>>(D1, D2, sv);

  // operand prep
  convert_bf16<<<2048, 256, 0, stream>>>((const float4*)X, (u16x4*)Xbf, N * F / 4);
  transpose_cvt<<<(F * H) / 256, 256, 0, stream>>>(W1, W1T, F, H);
  transpose_cvt<<<(H * Cc) / 256, 256, 0, stream>>>(W2, W2T, H, Cc);

  // gemm1: XW1T[H][N] = W1T[H][F] @ X^T, epi: (acc+b1[row])*s[col]
  gemm_bt<128, 128, 3><<<dim3(H / 128, N / 128, 1), 256, 0, stream>>>(
      W1T, Xbf, XW1T, b1, sv, H, N, F, F, N);

  // gemm2: h[N][H] = tilde_bf @ (s*XW1) (BT = XW1T), relu.  split-K=4 if ws allows.
  if (splitk2) {
    gemm_bt<128, 128, 2><<<dim3(N / 128, H / 128, 4), 256, 0, stream>>>(
        Tbf, XW1T, part2, nullptr, nullptr, N, H, N, N / 4, H);
    reduce_relu_bf16<<<1024, 256, 0, stream>>>((const float4*)part2, (u16x4*)hbuf,
                                               N * H / 4, 4);
  } else {
    gemm_bt<128, 128, 1><<<dim3(N / 128, H / 128, 1), 256, 0, stream>>>(
        Tbf, XW1T, hbuf, nullptr, nullptr, N, H, N, N, H);
  }

  // gemm3: ZT[C][N] = W2T[C][H] @ h^T (BT = hbuf), epi: (acc+b2[row])*s[col]
  gemm_bt<64, 128, 3><<<dim3(Cc / 64, N / 128, 1), 256, 0, stream>>>(
      W2T, hbuf, ZT, b2, sv, Cc, N, H, H, N);

  // gemm4: out[N][C] = tilde_bf @ (s*Z) (BT = ZT), split-K=8, f32 partials
  gemm_bt<128, 64, 2><<<dim3(N / 128, 1, 8), 256, 0, stream>>>(
      Tbf, ZT, part4, nullptr, nullptr, N, Cc, N, N / 8, Cc);
  reduce_f32<<<512, 256, 0, stream>>>((const float4*)part4, (float4*)out, N * Cc / 4, 8);
}

// Round 4
// 348.807 us; speedup vs baseline: 1.4174x; 1.4174x over previous
//
#include <hip/hip_runtime.h>
#include <hip/hip_bf16.h>
#include <cstdint>
#include <cstddef>

// ---------- types ----------
typedef __attribute__((ext_vector_type(8))) __bf16 bf16x8;
typedef __attribute__((ext_vector_type(4))) float f32x4;
typedef __attribute__((ext_vector_type(4))) unsigned short u16x4;

#define DEVINL static __device__ __forceinline__

DEVINL unsigned short f2bf(float x) {
  union { float f; unsigned u; } un; un.f = x;
  unsigned r = un.u + 0x7fffu + ((un.u >> 16) & 1u);
  return (unsigned short)(r >> 16);
}

DEVINL void gload16(const void* g, void* l) {
  __builtin_amdgcn_global_load_lds(
      (__attribute__((address_space(1))) void*)(void*)(uintptr_t)(const void*)g,
      (__attribute__((address_space(3))) void*)l, 16, 0, 0);
}

// ---------- fused: sums of tilde + convert tilde -> bf16. NO ATOMICS. ----------
// 1024 blocks x 8 rows. Column partials -> plain coalesced stores to partials[b][8192].
// Row sums -> LDS cross-wave reduce -> plain store (each row owned by one block).
__global__ __launch_bounds__(256, 4) void sums_convert(const float* __restrict__ tilde,
                                                       float4* __restrict__ partials4,
                                                       float* __restrict__ D2,
                                                       u16x4* __restrict__ Tbf) {
  const int t = threadIdx.x;
  float4 ca[8];
#pragma unroll
  for (int i = 0; i < 8; ++i) ca[i] = (float4){0.f, 0.f, 0.f, 0.f};
  float rs[8];
#pragma unroll
  for (int r = 0; r < 8; ++r) rs[r] = 0.f;

  const int base_row = blockIdx.x * 8;
#pragma unroll
  for (int r = 0; r < 8; ++r) {
    const size_t rowoff = (size_t)(base_row + r) * 2048;  // float4 units
    const float4* rp = (const float4*)tilde + rowoff;
    u16x4* op = Tbf + rowoff;
#pragma unroll
    for (int i = 0; i < 8; ++i) {
      float4 v = rp[t + i * 256];
      ca[i].x += v.x; ca[i].y += v.y; ca[i].z += v.z; ca[i].w += v.w;
      rs[r] += (v.x + v.y) + (v.z + v.w);
      u16x4 o;
      o[0] = f2bf(v.x); o[1] = f2bf(v.y); o[2] = f2bf(v.z); o[3] = f2bf(v.w);
      op[t + i * 256] = o;
    }
  }
  // column partials: plain coalesced float4 stores
  float4* pb = partials4 + (size_t)blockIdx.x * 2048;
#pragma unroll
  for (int i = 0; i < 8; ++i) pb[t + i * 256] = ca[i];

  // row sums: wave shuffle + LDS cross-wave combine, plain store
#pragma unroll
  for (int r = 0; r < 8; ++r) {
#pragma unroll
    for (int off = 32; off > 0; off >>= 1) rs[r] += __shfl_down(rs[r], off, 64);
  }
  __shared__ float wsum[4][8];
  const int wave = t >> 6;
  if ((t & 63) == 0) {
#pragma unroll
    for (int r = 0; r < 8; ++r) wsum[wave][r] = rs[r];
  }
  __syncthreads();
  if (t < 8) D2[base_row + t] = wsum[0][t] + wsum[1][t] + wsum[2][t] + wsum[3][t];
}

// ---------- reduce partials over z-chunks: partials[1024][8192] -> partials2[8][8192] ----------
__global__ __launch_bounds__(256) void zreduce(const float4* __restrict__ partials4,
                                               float4* __restrict__ partials2_4) {
  const int c4 = blockIdx.x * 256 + threadIdx.x;   // float4 column 0..2047
  const int z0 = blockIdx.y * 128;
  float4 s = (float4){0.f, 0.f, 0.f, 0.f};
#pragma unroll 4
  for (int z = z0; z < z0 + 128; ++z) {
    float4 v = partials4[(size_t)z * 2048 + c4];
    s.x += v.x; s.y += v.y; s.z += v.z; s.w += v.w;
  }
  partials2_4[(size_t)blockIdx.y * 2048 + c4] = s;
}

// ---------- sv[j] = sqrt(colsum[j] * D2[j]) ----------
__global__ __launch_bounds__(256) void colscale_kernel(const float* __restrict__ partials2,
                                                       const float* __restrict__ D2,
                                                       float* __restrict__ sv) {
  int j = blockIdx.x * 256 + threadIdx.x;
  float d1 = 0.f;
#pragma unroll
  for (int z = 0; z < 8; ++z) d1 += partials2[z * 8192 + j];
  sv[j] = sqrtf(d1 * D2[j]);
}

// ---------- fp32 -> bf16 convert ----------
__global__ __launch_bounds__(256) void convert_bf16(const float4* __restrict__ in,
                                                    u16x4* __restrict__ out, int n4) {
  const int stride = gridDim.x * 256;
  for (int i = blockIdx.x * 256 + threadIdx.x; i < n4; i += stride) {
    float4 v = in[i];
    u16x4 o;
    o[0] = f2bf(v.x); o[1] = f2bf(v.y); o[2] = f2bf(v.z); o[3] = f2bf(v.w);
    out[i] = o;
  }
}

// ---------- transpose + convert: out[c][r] = bf16(in[r][c]) ----------
__global__ __launch_bounds__(256) void transpose_cvt(const float* __restrict__ in,
                                                     unsigned short* __restrict__ out,
                                                     int R, int C) {
  int o = blockIdx.x * 256 + threadIdx.x;
  if (o >= R * C) return;
  int c = o / R, r = o - c * R;
  out[o] = f2bf(in[(size_t)r * C + c]);
}

// ---------- tiled MFMA GEMM: C[M,N] = A[M,K] @ B[K,N], BT given as [N][K] ----------
// EPI: 1 = bf16 out + relu; 2 = f32 partial out (split-K); 3 = bf16 out, (acc+bias[row])*cs[col]
template <int BM, int BN, int EPI>
__global__ __launch_bounds__(256) void gemm_bt(
    const unsigned short* __restrict__ A,   // [M][K] bf16 row-major
    const unsigned short* __restrict__ BT,  // [N][K] bf16 row-major
    void* __restrict__ C,
    const float* __restrict__ bias,
    const float* __restrict__ cs,
    int M, int N, int K, int kChunk, int ldc) {
  constexpr int WTM = BM / 2, WTN = BN / 2;
  constexpr int MR = WTM / 16, NR = WTN / 16;
  constexpr int AIT = BM * 4 / 256;
  constexpr int BIT = BN * 4 / 256;

  __shared__ unsigned short As[BM * 32];
  __shared__ unsigned short Bs[BN * 32];

  const int t = threadIdx.x;
  const int lane = t & 63, wave = t >> 6;
  const int wr = wave >> 1, wc = wave & 1;
  const int bm = blockIdx.x, bn = blockIdx.y, bz = blockIdx.z;
  const int row0 = bm * BM, col0 = bn * BN;
  const int kbeg = bz * kChunk, kend = kbeg + kChunk;
  const int lrow = lane & 15;
  const int lk = (lane >> 4) * 8;

  f32x4 acc[MR][NR];
#pragma unroll
  for (int m = 0; m < MR; ++m)
#pragma unroll
    for (int n = 0; n < NR; ++n) acc[m][n] = (f32x4){0.f, 0.f, 0.f, 0.f};

  for (int k0 = kbeg; k0 < kend; k0 += 32) {
#pragma unroll
    for (int i = 0; i < AIT; ++i) {
      int flat = i * 256 + t;
      int r = flat >> 2, ko = (flat & 3) * 8;
      gload16(A + (size_t)(row0 + r) * K + k0 + ko, As + (size_t)flat * 8);
    }
#pragma unroll
    for (int i = 0; i < BIT; ++i) {
      int flat = i * 256 + t;
      int r = flat >> 2, ko = (flat & 3) * 8;
      gload16(BT + (size_t)(col0 + r) * K + k0 + ko, Bs + (size_t)flat * 8);
    }
    __syncthreads();

    bf16x8 af[MR], bfr[NR];
#pragma unroll
    for (int m = 0; m < MR; ++m)
      af[m] = *(const bf16x8*)&As[(wr * WTM + m * 16 + lrow) * 32 + lk];
#pragma unroll
    for (int n = 0; n < NR; ++n)
      bfr[n] = *(const bf16x8*)&Bs[(wc * WTN + n * 16 + lrow) * 32 + lk];
#pragma unroll
    for (int m = 0; m < MR; ++m)
#pragma unroll
      for (int n = 0; n < NR; ++n)
        acc[m][n] = __builtin_amdgcn_mfma_f32_16x16x32_bf16(af[m], bfr[n], acc[m][n], 0, 0, 0);
    __syncthreads();
  }

  const int r0 = row0 + wr * WTM, c0 = col0 + wc * WTN;
  if constexpr (EPI == 2) {
    float* Cf = (float*)C + (size_t)bz * M * ldc;
#pragma unroll
    for (int m = 0; m < MR; ++m)
#pragma unroll
      for (int n = 0; n < NR; ++n)
#pragma unroll
        for (int j = 0; j < 4; ++j) {
          int row = r0 + m * 16 + (lane >> 4) * 4 + j;
          int col = c0 + n * 16 + lrow;
          Cf[(size_t)row * ldc + col] = acc[m][n][j];
        }
  } else {
    unsigned short* Cb = (unsigned short*)C;
#pragma unroll
    for (int m = 0; m < MR; ++m)
#pragma unroll
      for (int n = 0; n < NR; ++n)
#pragma unroll
        for (int j = 0; j < 4; ++j) {
          int row = r0 + m * 16 + (lane >> 4) * 4 + j;
          int col = c0 + n * 16 + lrow;
          float v = acc[m][n][j];
          if constexpr (EPI == 1) v = v > 0.f ? v : 0.f;
          if constexpr (EPI == 3) v = (v + bias[row]) * cs[col];
          Cb[(size_t)row * ldc + col] = f2bf(v);
        }
  }
}

// ---------- reduce split-K partials -> relu -> bf16 ----------
__global__ __launch_bounds__(256) void reduce_relu_bf16(const float4* __restrict__ part,
                                                        u16x4* __restrict__ out,
                                                        int total4, int splits) {
  const int stride = gridDim.x * 256;
  for (int i = blockIdx.x * 256 + threadIdx.x; i < total4; i += stride) {
    float4 s = part[i];
    for (int z = 1; z < splits; ++z) {
      float4 v = part[(size_t)z * total4 + i];
      s.x += v.x; s.y += v.y; s.z += v.z; s.w += v.w;
    }
    u16x4 o;
    o[0] = f2bf(s.x > 0.f ? s.x : 0.f);
    o[1] = f2bf(s.y > 0.f ? s.y : 0.f);
    o[2] = f2bf(s.z > 0.f ? s.z : 0.f);
    o[3] = f2bf(s.w > 0.f ? s.w : 0.f);
    out[i] = o;
  }
}

// ---------- reduce split-K partials -> f32 ----------
__global__ __launch_bounds__(256) void reduce_f32(const float4* __restrict__ part,
                                                  float4* __restrict__ out,
                                                  int total4, int splits) {
  const int stride = gridDim.x * 256;
  for (int i = blockIdx.x * 256 + threadIdx.x; i < total4; i += stride) {
    float4 s = part[i];
    for (int z = 1; z < splits; ++z) {
      float4 v = part[(size_t)z * total4 + i];
      s.x += v.x; s.y += v.y; s.z += v.z; s.w += v.w;
    }
    out[i] = s;
  }
}

// ---------- launch ----------
extern "C" void kernel_launch(void* const* d_in, const int* in_sizes, int n_in,
                              void* d_out, int out_size, void* d_ws, size_t ws_size,
                              hipStream_t stream) {
  const float* X     = (const float*)d_in[0];
  const float* tilde = (const float*)d_in[1];
  const float* W1    = (const float*)d_in[2];
  const float* b1    = (const float*)d_in[3];
  const float* W2    = (const float*)d_in[4];
  const float* b2    = (const float*)d_in[5];
  float* out = (float*)d_out;

  constexpr int N = 8192, F = 1024, H = 512, Cc = 64;

  char* ws = (char*)d_ws;
  size_t off = 0;
  auto alloc = [&](size_t bytes) {
    char* p = ws + off;
    off += (bytes + 255) & ~(size_t)255;
    return p;
  };
  // persistent-ish region
  unsigned short* Tbf  = (unsigned short*)alloc((size_t)N * N * 2);   // 128 MB (live thru gemm4)
  unsigned short* XW1T = (unsigned short*)alloc((size_t)H * N * 2);   // 8 MB  (dead after gemm2)
  unsigned short* hbuf = (unsigned short*)alloc((size_t)N * H * 2);   // 8 MB  (dead after gemm3)
  unsigned short* ZT   = (unsigned short*)alloc((size_t)Cc * N * 2);  // 1 MB  (dead after gemm4)
  unsigned short* W2T  = (unsigned short*)alloc((size_t)Cc * H * 2);  // 64 KB
  float* partials2 = (float*)alloc(8 * N * 4);                        // 256 KB
  float* D2 = (float*)alloc(N * 4);
  float* sv = (float*)alloc(N * 4);
  // scratch zone (serial reuse):
  //   phase A: [Xbf 16MB | W1T 1MB | partials 32MB]
  //   phase B: [part2 64MB]    phase C: [part4 16MB]
  const size_t scratch_base = off;
  unsigned short* Xbf = (unsigned short*)(ws + scratch_base);                      // 16 MB
  unsigned short* W1T = (unsigned short*)(ws + scratch_base + (size_t)N * F * 2);  // 1 MB
  float* partials = (float*)(ws + scratch_base + (size_t)N * F * 2 + 0x200000);    // 32 MB
  float* part2 = (float*)(ws + scratch_base);  // 4 * 8192*512*4 = 64 MB
  float* part4 = (float*)(ws + scratch_base);  // 8 * 8192*64*4  = 16 MB

  const size_t need_split = scratch_base + (size_t)4 * N * H * 4;     // ~210 MB
  const bool splitk2 = ws_size >= need_split;

  // fused sums + tilde->bf16 (A never materialized; scale folded into epilogues)
  sums_convert<<<1024, 256, 0, stream>>>(tilde, (float4*)partials, D2, (u16x4*)Tbf);
  zreduce<<<dim3(8, 8), 256, 0, stream>>>((const float4*)partials, (float4*)partials2);
  colscale_kernel<<<N / 256, 256, 0, stream>>>(partials2, D2, sv);

  // operand prep
  convert_bf16<<<2048, 256, 0, stream>>>((const float4*)X, (u16x4*)Xbf, N * F / 4);
  transpose_cvt<<<(F * H) / 256, 256, 0, stream>>>(W1, W1T, F, H);
  transpose_cvt<<<(H * Cc) / 256, 256, 0, stream>>>(W2, W2T, H, Cc);

  // gemm1: XW1T[H][N] = W1T[H][F] @ X^T, epi: (acc+b1[row])*s[col]
  gemm_bt<128, 128, 3><<<dim3(H / 128, N / 128, 1), 256, 0, stream>>>(
      W1T, Xbf, XW1T, b1, sv, H, N, F, F, N);

  // gemm2: h[N][H] = tilde_bf @ (s*XW1) (BT = XW1T), relu.  split-K=4 if ws allows.
  if (splitk2) {
    gemm_bt<128, 128, 2><<<dim3(N / 128, H / 128, 4), 256, 0, stream>>>(
        Tbf, XW1T, part2, nullptr, nullptr, N, H, N, N / 4, H);
    reduce_relu_bf16<<<1024, 256, 0, stream>>>((const float4*)part2, (u16x4*)hbuf,
                                               N * H / 4, 4);
  } else {
    gemm_bt<128, 128, 1><<<dim3(N / 128, H / 128, 1), 256, 0, stream>>>(
        Tbf, XW1T, hbuf, nullptr, nullptr, N, H, N, N, H);
  }

  // gemm3: ZT[C][N] = W2T[C][H] @ h^T (BT = hbuf), epi: (acc+b2[row])*s[col]
  gemm_bt<64, 128, 3><<<dim3(Cc / 64, N / 128, 1), 256, 0, stream>>>(
      W2T, hbuf, ZT, b2, sv, Cc, N, H, H, N);

  // gemm4: out[N][C] = tilde_bf @ (s*Z) (BT = ZT), split-K=8, f32 partials
  gemm_bt<128, 64, 2><<<dim3(N / 128, 1, 8), 256, 0, stream>>>(
      Tbf, ZT, part4, nullptr, nullptr, N, Cc, N, N / 8, Cc);
  reduce_f32<<<512, 256, 0, stream>>>((const float4*)part4, (float4*)out, N * Cc / 4, 8);
}

// Round 5
// 342.585 us; speedup vs baseline: 1.4432x; 1.0182x over previous
//
#include <hip/hip_runtime.h>
#include <hip/hip_bf16.h>
#include <cstdint>
#include <cstddef>

// ---------- types ----------
typedef __attribute__((ext_vector_type(8))) __bf16 bf16x8;
typedef __attribute__((ext_vector_type(4))) float f32x4;
typedef __attribute__((ext_vector_type(4))) unsigned short u16x4;

#define DEVINL static __device__ __forceinline__

DEVINL unsigned short f2bf(float x) {
  union { float f; unsigned u; } un; un.f = x;
  unsigned r = un.u + 0x7fffu + ((un.u >> 16) & 1u);
  return (unsigned short)(r >> 16);
}

DEVINL float bf2f(unsigned short b) {
  union { unsigned u; float f; } un; un.u = ((unsigned)b) << 16;
  return un.f;
}

DEVINL void gload16(const void* g, void* l) {
  __builtin_amdgcn_global_load_lds(
      (__attribute__((address_space(1))) void*)(void*)(uintptr_t)(const void*)g,
      (__attribute__((address_space(3))) void*)l, 16, 0, 0);
}

// ---------- fused: sums of tilde + convert tilde -> bf16. NO ATOMICS. ----------
__global__ __launch_bounds__(256, 4) void sums_convert(const float* __restrict__ tilde,
                                                       float4* __restrict__ partials4,
                                                       float* __restrict__ D2,
                                                       u16x4* __restrict__ Tbf) {
  const int t = threadIdx.x;
  float4 ca[8];
#pragma unroll
  for (int i = 0; i < 8; ++i) ca[i] = (float4){0.f, 0.f, 0.f, 0.f};
  float rs[8];
#pragma unroll
  for (int r = 0; r < 8; ++r) rs[r] = 0.f;

  const int base_row = blockIdx.x * 8;
#pragma unroll
  for (int r = 0; r < 8; ++r) {
    const size_t rowoff = (size_t)(base_row + r) * 2048;  // float4 units
    const float4* rp = (const float4*)tilde + rowoff;
    u16x4* op = Tbf + rowoff;
#pragma unroll
    for (int i = 0; i < 8; ++i) {
      float4 v = rp[t + i * 256];
      ca[i].x += v.x; ca[i].y += v.y; ca[i].z += v.z; ca[i].w += v.w;
      rs[r] += (v.x + v.y) + (v.z + v.w);
      u16x4 o;
      o[0] = f2bf(v.x); o[1] = f2bf(v.y); o[2] = f2bf(v.z); o[3] = f2bf(v.w);
      op[t + i * 256] = o;
    }
  }
  float4* pb = partials4 + (size_t)blockIdx.x * 2048;
#pragma unroll
  for (int i = 0; i < 8; ++i) pb[t + i * 256] = ca[i];

#pragma unroll
  for (int r = 0; r < 8; ++r) {
#pragma unroll
    for (int off = 32; off > 0; off >>= 1) rs[r] += __shfl_down(rs[r], off, 64);
  }
  __shared__ float wsum[4][8];
  const int wave = t >> 6;
  if ((t & 63) == 0) {
#pragma unroll
    for (int r = 0; r < 8; ++r) wsum[wave][r] = rs[r];
  }
  __syncthreads();
  if (t < 8) D2[base_row + t] = wsum[0][t] + wsum[1][t] + wsum[2][t] + wsum[3][t];
}

// ---------- reduce partials over z-chunks: partials[1024][8192] -> partials2[8][8192] ----------
__global__ __launch_bounds__(256) void zreduce(const float4* __restrict__ partials4,
                                               float4* __restrict__ partials2_4) {
  const int c4 = blockIdx.x * 256 + threadIdx.x;
  const int z0 = blockIdx.y * 128;
  float4 s = (float4){0.f, 0.f, 0.f, 0.f};
#pragma unroll 4
  for (int z = z0; z < z0 + 128; ++z) {
    float4 v = partials4[(size_t)z * 2048 + c4];
    s.x += v.x; s.y += v.y; s.z += v.z; s.w += v.w;
  }
  partials2_4[(size_t)blockIdx.y * 2048 + c4] = s;
}

// ---------- sv[j] = sqrt(colsum[j] * D2[j]) ----------
__global__ __launch_bounds__(256) void colscale_kernel(const float* __restrict__ partials2,
                                                       const float* __restrict__ D2,
                                                       float* __restrict__ sv) {
  int j = blockIdx.x * 256 + threadIdx.x;
  float d1 = 0.f;
#pragma unroll
  for (int z = 0; z < 8; ++z) d1 += partials2[z * 8192 + j];
  sv[j] = sqrtf(d1 * D2[j]);
}

// ---------- fp32 -> bf16 convert ----------
__global__ __launch_bounds__(256) void convert_bf16(const float4* __restrict__ in,
                                                    u16x4* __restrict__ out, int n4) {
  const int stride = gridDim.x * 256;
  for (int i = blockIdx.x * 256 + threadIdx.x; i < n4; i += stride) {
    float4 v = in[i];
    u16x4 o;
    o[0] = f2bf(v.x); o[1] = f2bf(v.y); o[2] = f2bf(v.z); o[3] = f2bf(v.w);
    out[i] = o;
  }
}

// ---------- transpose + convert: out[c][r] = bf16(in[r][c]) ----------
__global__ __launch_bounds__(256) void transpose_cvt(const float* __restrict__ in,
                                                     unsigned short* __restrict__ out,
                                                     int R, int C) {
  int o = blockIdx.x * 256 + threadIdx.x;
  if (o >= R * C) return;
  int c = o / R, r = o - c * R;
  out[o] = f2bf(in[(size_t)r * C + c]);
}

// ---------- tiled MFMA GEMM: C[M,N] = A[M,K] @ B[K,N], BT given as [N][K] ----------
// EPI: 1 = bf16 out + relu; 2 = f32 partial (split-K); 3 = bf16 out, (acc+bias[row])*cs[col];
//      4 = bf16 partial (split-K)
template <int BM, int BN, int EPI>
__global__ __launch_bounds__(256) void gemm_bt(
    const unsigned short* __restrict__ A,   // [M][K] bf16 row-major
    const unsigned short* __restrict__ BT,  // [N][K] bf16 row-major
    void* __restrict__ C,
    const float* __restrict__ bias,
    const float* __restrict__ cs,
    int M, int N, int K, int kChunk, int ldc) {
  constexpr int WTM = BM / 2, WTN = BN / 2;
  constexpr int MR = WTM / 16, NR = WTN / 16;
  constexpr int AIT = BM * 4 / 256;
  constexpr int BIT = BN * 4 / 256;

  __shared__ unsigned short As[BM * 32];
  __shared__ unsigned short Bs[BN * 32];

  const int t = threadIdx.x;
  const int lane = t & 63, wave = t >> 6;
  const int wr = wave >> 1, wc = wave & 1;
  const int bm = blockIdx.x, bn = blockIdx.y, bz = blockIdx.z;
  const int row0 = bm * BM, col0 = bn * BN;
  const int kbeg = bz * kChunk, kend = kbeg + kChunk;
  const int lrow = lane & 15;
  const int lk = (lane >> 4) * 8;

  f32x4 acc[MR][NR];
#pragma unroll
  for (int m = 0; m < MR; ++m)
#pragma unroll
    for (int n = 0; n < NR; ++n) acc[m][n] = (f32x4){0.f, 0.f, 0.f, 0.f};

  for (int k0 = kbeg; k0 < kend; k0 += 32) {
#pragma unroll
    for (int i = 0; i < AIT; ++i) {
      int flat = i * 256 + t;
      int r = flat >> 2, ko = (flat & 3) * 8;
      gload16(A + (size_t)(row0 + r) * K + k0 + ko, As + (size_t)flat * 8);
    }
#pragma unroll
    for (int i = 0; i < BIT; ++i) {
      int flat = i * 256 + t;
      int r = flat >> 2, ko = (flat & 3) * 8;
      gload16(BT + (size_t)(col0 + r) * K + k0 + ko, Bs + (size_t)flat * 8);
    }
    __syncthreads();

    bf16x8 af[MR], bfr[NR];
#pragma unroll
    for (int m = 0; m < MR; ++m)
      af[m] = *(const bf16x8*)&As[(wr * WTM + m * 16 + lrow) * 32 + lk];
#pragma unroll
    for (int n = 0; n < NR; ++n)
      bfr[n] = *(const bf16x8*)&Bs[(wc * WTN + n * 16 + lrow) * 32 + lk];
#pragma unroll
    for (int m = 0; m < MR; ++m)
#pragma unroll
      for (int n = 0; n < NR; ++n)
        acc[m][n] = __builtin_amdgcn_mfma_f32_16x16x32_bf16(af[m], bfr[n], acc[m][n], 0, 0, 0);
    __syncthreads();
  }

  const int r0 = row0 + wr * WTM, c0 = col0 + wc * WTN;
  if constexpr (EPI == 2) {
    float* Cf = (float*)C + (size_t)bz * M * ldc;
#pragma unroll
    for (int m = 0; m < MR; ++m)
#pragma unroll
      for (int n = 0; n < NR; ++n)
#pragma unroll
        for (int j = 0; j < 4; ++j) {
          int row = r0 + m * 16 + (lane >> 4) * 4 + j;
          int col = c0 + n * 16 + lrow;
          Cf[(size_t)row * ldc + col] = acc[m][n][j];
        }
  } else if constexpr (EPI == 4) {
    unsigned short* Cb = (unsigned short*)C + (size_t)bz * M * ldc;
#pragma unroll
    for (int m = 0; m < MR; ++m)
#pragma unroll
      for (int n = 0; n < NR; ++n)
#pragma unroll
        for (int j = 0; j < 4; ++j) {
          int row = r0 + m * 16 + (lane >> 4) * 4 + j;
          int col = c0 + n * 16 + lrow;
          Cb[(size_t)row * ldc + col] = f2bf(acc[m][n][j]);
        }
  } else {
    unsigned short* Cb = (unsigned short*)C;
#pragma unroll
    for (int m = 0; m < MR; ++m)
#pragma unroll
      for (int n = 0; n < NR; ++n)
#pragma unroll
        for (int j = 0; j < 4; ++j) {
          int row = r0 + m * 16 + (lane >> 4) * 4 + j;
          int col = c0 + n * 16 + lrow;
          float v = acc[m][n][j];
          if constexpr (EPI == 1) v = v > 0.f ? v : 0.f;
          if constexpr (EPI == 3) v = (v + bias[row]) * cs[col];
          Cb[(size_t)row * ldc + col] = f2bf(v);
        }
  }
}

// ---------- reduce bf16 split-K partials -> relu -> bf16 ----------
__global__ __launch_bounds__(256) void reduce_relu_b16p(const u16x4* __restrict__ part,
                                                        u16x4* __restrict__ out,
                                                        int total4, int splits) {
  const int stride = gridDim.x * 256;
  for (int i = blockIdx.x * 256 + threadIdx.x; i < total4; i += stride) {
    float s0 = 0.f, s1 = 0.f, s2 = 0.f, s3 = 0.f;
    for (int z = 0; z < splits; ++z) {
      u16x4 v = part[(size_t)z * total4 + i];
      s0 += bf2f(v[0]); s1 += bf2f(v[1]); s2 += bf2f(v[2]); s3 += bf2f(v[3]);
    }
    u16x4 o;
    o[0] = f2bf(s0 > 0.f ? s0 : 0.f);
    o[1] = f2bf(s1 > 0.f ? s1 : 0.f);
    o[2] = f2bf(s2 > 0.f ? s2 : 0.f);
    o[3] = f2bf(s3 > 0.f ? s3 : 0.f);
    out[i] = o;
  }
}

// ---------- reduce gemm3 f32 partials -> (s+b2[row])*sv[col] -> bf16 ZT[64][8192] ----------
__global__ __launch_bounds__(256) void reduce_zt(const float4* __restrict__ part,
                                                 const float* __restrict__ b2,
                                                 const float* __restrict__ sv,
                                                 u16x4* __restrict__ out) {
  const int i4 = blockIdx.x * 256 + threadIdx.x;  // over 64*8192/4 = 131072
  const int row = i4 >> 11;
  const int col0 = (i4 & 2047) * 4;
  float4 s = part[i4];
#pragma unroll
  for (int z = 1; z < 4; ++z) {
    float4 v = part[(size_t)z * 131072 + i4];
    s.x += v.x; s.y += v.y; s.z += v.z; s.w += v.w;
  }
  const float b = b2[row];
  u16x4 o;
  o[0] = f2bf((s.x + b) * sv[col0 + 0]);
  o[1] = f2bf((s.y + b) * sv[col0 + 1]);
  o[2] = f2bf((s.z + b) * sv[col0 + 2]);
  o[3] = f2bf((s.w + b) * sv[col0 + 3]);
  out[i4] = o;
}

// ---------- reduce split-K partials -> f32 ----------
__global__ __launch_bounds__(256) void reduce_f32(const float4* __restrict__ part,
                                                  float4* __restrict__ out,
                                                  int total4, int splits) {
  const int stride = gridDim.x * 256;
  for (int i = blockIdx.x * 256 + threadIdx.x; i < total4; i += stride) {
    float4 s = part[i];
    for (int z = 1; z < splits; ++z) {
      float4 v = part[(size_t)z * total4 + i];
      s.x += v.x; s.y += v.y; s.z += v.z; s.w += v.w;
    }
    out[i] = s;
  }
}

// ---------- launch ----------
extern "C" void kernel_launch(void* const* d_in, const int* in_sizes, int n_in,
                              void* d_out, int out_size, void* d_ws, size_t ws_size,
                              hipStream_t stream) {
  const float* X     = (const float*)d_in[0];
  const float* tilde = (const float*)d_in[1];
  const float* W1    = (const float*)d_in[2];
  const float* b1    = (const float*)d_in[3];
  const float* W2    = (const float*)d_in[4];
  const float* b2    = (const float*)d_in[5];
  float* out = (float*)d_out;

  constexpr int N = 8192, F = 1024, H = 512, Cc = 64;

  char* ws = (char*)d_ws;
  size_t off = 0;
  auto alloc = [&](size_t bytes) {
    char* p = ws + off;
    off += (bytes + 255) & ~(size_t)255;
    return p;
  };
  // persistent region
  unsigned short* Tbf  = (unsigned short*)alloc((size_t)N * N * 2);   // 128 MB
  unsigned short* XW1T = (unsigned short*)alloc((size_t)H * N * 2);   // 8 MB
  unsigned short* hbuf = (unsigned short*)alloc((size_t)N * H * 2);   // 8 MB
  unsigned short* ZT   = (unsigned short*)alloc((size_t)Cc * N * 2);  // 1 MB
  unsigned short* W2T  = (unsigned short*)alloc((size_t)Cc * H * 2);  // 64 KB
  float* partials2 = (float*)alloc(8 * N * 4);                        // 256 KB
  float* D2 = (float*)alloc(N * 4);
  float* sv = (float*)alloc(N * 4);
  // scratch zone (serial reuse):
  //  A: [Xbf 16MB | W1T 2MB pad | partials 32MB]  (partials dead after zreduce,
  //     Xbf/W1T dead after gemm1)
  //  B: part2 bf16 32MB   C: part3 f32 8MB   D: part4 f32 16MB
  const size_t scratch_base = off;
  unsigned short* Xbf = (unsigned short*)(ws + scratch_base);                      // 16 MB
  unsigned short* W1T = (unsigned short*)(ws + scratch_base + (size_t)N * F * 2);  // 1 MB
  float* partials = (float*)(ws + scratch_base + (size_t)N * F * 2 + 0x200000);    // 32 MB
  unsigned short* part2 = (unsigned short*)(ws + scratch_base);  // 4*8192*512*2 = 32 MB
  float* part3 = (float*)(ws + scratch_base);                    // 4*64*8192*4  = 8 MB
  float* part4 = (float*)(ws + scratch_base);                    // 8*8192*64*4  = 16 MB

  const size_t need_split = scratch_base + (size_t)N * F * 2 + 0x200000 + (size_t)1024 * N * 4;
  const bool splitk = ws_size >= need_split;

  // fused sums + tilde->bf16 (A never materialized; scale folded into epilogues)
  sums_convert<<<1024, 256, 0, stream>>>(tilde, (float4*)partials, D2, (u16x4*)Tbf);
  zreduce<<<dim3(8, 8), 256, 0, stream>>>((const float4*)partials, (float4*)partials2);
  colscale_kernel<<<N / 256, 256, 0, stream>>>(partials2, D2, sv);

  // operand prep
  convert_bf16<<<2048, 256, 0, stream>>>((const float4*)X, (u16x4*)Xbf, N * F / 4);
  transpose_cvt<<<(F * H) / 256, 256, 0, stream>>>(W1, W1T, F, H);
  transpose_cvt<<<(H * Cc) / 256, 256, 0, stream>>>(W2, W2T, H, Cc);

  // gemm1: XW1T[H][N] = W1T[H][F] @ X^T, epi: (acc+b1[row])*s[col]
  gemm_bt<128, 128, 3><<<dim3(H / 128, N / 128, 1), 256, 0, stream>>>(
      W1T, Xbf, XW1T, b1, sv, H, N, F, F, N);

  if (splitk) {
    // gemm2: h[N][H] = tilde_bf @ (s*XW1), split-K=4, bf16 partials
    gemm_bt<128, 128, 4><<<dim3(N / 128, H / 128, 4), 256, 0, stream>>>(
        Tbf, XW1T, part2, nullptr, nullptr, N, H, N, N / 4, H);
    reduce_relu_b16p<<<1024, 256, 0, stream>>>((const u16x4*)part2, (u16x4*)hbuf,
                                               N * H / 4, 4);
    // gemm3: ZT[C][N] = W2T[C][H] @ h^T, split-K=4, f32 partials; epi in reduce_zt
    gemm_bt<64, 128, 2><<<dim3(1, N / 128, 4), 256, 0, stream>>>(
        W2T, hbuf, part3, nullptr, nullptr, Cc, N, H, H / 4, N);
    reduce_zt<<<(Cc * N / 4) / 256, 256, 0, stream>>>((const float4*)part3, b2, sv,
                                                      (u16x4*)ZT);
  } else {
    gemm_bt<128, 128, 1><<<dim3(N / 128, H / 128, 1), 256, 0, stream>>>(
        Tbf, XW1T, hbuf, nullptr, nullptr, N, H, N, N, H);
    gemm_bt<64, 128, 3><<<dim3(1, N / 128, 1), 256, 0, stream>>>(
        W2T, hbuf, ZT, b2, sv, Cc, N, H, H, N);
  }

  // gemm4: out[N][C] = tilde_bf @ (s*Z) (BT = ZT), split-K=8, f32 partials
  gemm_bt<128, 64, 2><<<dim3(N / 128, 1, 8), 256, 0, stream>>>(
      Tbf, ZT, part4, nullptr, nullptr, N, Cc, N, N / 8, Cc);
  reduce_f32<<<512, 256, 0, stream>>>((const float4*)part4, (float4*)out, N * Cc / 4, 8);
}

// Round 6
// 334.177 us; speedup vs baseline: 1.4795x; 1.0252x over previous
//
#include <hip/hip_runtime.h>
#include <hip/hip_bf16.h>
#include <cstdint>
#include <cstddef>

// ---------- types ----------
typedef __attribute__((ext_vector_type(8))) __bf16 bf16x8;
typedef __attribute__((ext_vector_type(4))) float f32x4;
typedef __attribute__((ext_vector_type(4))) unsigned short u16x4;

#define DEVINL static __device__ __forceinline__

DEVINL unsigned short f2bf(float x) {
  union { float f; unsigned u; } un; un.f = x;
  unsigned r = un.u + 0x7fffu + ((un.u >> 16) & 1u);
  return (unsigned short)(r >> 16);
}

DEVINL float bf2f(unsigned short b) {
  union { unsigned u; float f; } un; un.u = ((unsigned)b) << 16;
  return un.f;
}

DEVINL void gload16(const void* g, void* l) {
  __builtin_amdgcn_global_load_lds(
      (__attribute__((address_space(1))) void*)(void*)(uintptr_t)(const void*)g,
      (__attribute__((address_space(3))) void*)l, 16, 0, 0);
}

// ---------- fused: sums of tilde + convert tilde -> bf16. NO ATOMICS. ----------
__global__ __launch_bounds__(256, 4) void sums_convert(const float* __restrict__ tilde,
                                                       float4* __restrict__ partials4,
                                                       float* __restrict__ D2,
                                                       u16x4* __restrict__ Tbf) {
  const int t = threadIdx.x;
  float4 ca[8];
#pragma unroll
  for (int i = 0; i < 8; ++i) ca[i] = (float4){0.f, 0.f, 0.f, 0.f};
  float rs[8];
#pragma unroll
  for (int r = 0; r < 8; ++r) rs[r] = 0.f;

  const int base_row = blockIdx.x * 8;
#pragma unroll
  for (int r = 0; r < 8; ++r) {
    const size_t rowoff = (size_t)(base_row + r) * 2048;  // float4 units
    const float4* rp = (const float4*)tilde + rowoff;
    u16x4* op = Tbf + rowoff;
#pragma unroll
    for (int i = 0; i < 8; ++i) {
      float4 v = rp[t + i * 256];
      ca[i].x += v.x; ca[i].y += v.y; ca[i].z += v.z; ca[i].w += v.w;
      rs[r] += (v.x + v.y) + (v.z + v.w);
      u16x4 o;
      o[0] = f2bf(v.x); o[1] = f2bf(v.y); o[2] = f2bf(v.z); o[3] = f2bf(v.w);
      op[t + i * 256] = o;
    }
  }
  float4* pb = partials4 + (size_t)blockIdx.x * 2048;
#pragma unroll
  for (int i = 0; i < 8; ++i) pb[t + i * 256] = ca[i];

#pragma unroll
  for (int r = 0; r < 8; ++r) {
#pragma unroll
    for (int off = 32; off > 0; off >>= 1) rs[r] += __shfl_down(rs[r], off, 64);
  }
  __shared__ float wsum[4][8];
  const int wave = t >> 6;
  if ((t & 63) == 0) {
#pragma unroll
    for (int r = 0; r < 8; ++r) wsum[wave][r] = rs[r];
  }
  __syncthreads();
  if (t < 8) D2[base_row + t] = wsum[0][t] + wsum[1][t] + wsum[2][t] + wsum[3][t];
}

// ---------- reduce partials over z-chunks: partials[1024][8192] -> partials2[64][8192] ----------
__global__ __launch_bounds__(256) void zreduce(const float4* __restrict__ partials4,
                                               float4* __restrict__ partials2_4) {
  const int c4 = blockIdx.x * 256 + threadIdx.x;
  const int z0 = blockIdx.y * 16;
  float4 s = (float4){0.f, 0.f, 0.f, 0.f};
#pragma unroll 4
  for (int z = z0; z < z0 + 16; ++z) {
    float4 v = partials4[(size_t)z * 2048 + c4];
    s.x += v.x; s.y += v.y; s.z += v.z; s.w += v.w;
  }
  partials2_4[(size_t)blockIdx.y * 2048 + c4] = s;
}

// ---------- sv[j] = sqrt(colsum[j] * D2[j]) ----------
__global__ __launch_bounds__(256) void colscale_kernel(const float* __restrict__ partials2,
                                                       const float* __restrict__ D2,
                                                       float* __restrict__ sv) {
  int j = blockIdx.x * 256 + threadIdx.x;
  float d1 = 0.f;
  for (int z = 0; z < 64; ++z) d1 += partials2[z * 8192 + j];
  sv[j] = sqrtf(d1 * D2[j]);
}

// ---------- fp32 -> bf16 convert ----------
__global__ __launch_bounds__(256) void convert_bf16(const float4* __restrict__ in,
                                                    u16x4* __restrict__ out, int n4) {
  const int stride = gridDim.x * 256;
  for (int i = blockIdx.x * 256 + threadIdx.x; i < n4; i += stride) {
    float4 v = in[i];
    u16x4 o;
    o[0] = f2bf(v.x); o[1] = f2bf(v.y); o[2] = f2bf(v.z); o[3] = f2bf(v.w);
    out[i] = o;
  }
}

// ---------- transpose + convert: out[c][r] = bf16(in[r][c]) ----------
__global__ __launch_bounds__(256) void transpose_cvt(const float* __restrict__ in,
                                                     unsigned short* __restrict__ out,
                                                     int R, int C) {
  int o = blockIdx.x * 256 + threadIdx.x;
  if (o >= R * C) return;
  int c = o / R, r = o - c * R;
  out[o] = f2bf(in[(size_t)r * C + c]);
}

// ---------- tiled MFMA GEMM: C[M,N] = A[M,K] @ B[K,N], BT given as [N][K] ----------
// EPI: 1 = bf16 out + relu; 2 = f32 partial (split-K); 3 = bf16 out, (acc+bias[row])*cs[col];
//      4 = bf16 partial (split-K)
template <int BM, int BN, int EPI>
__global__ __launch_bounds__(256) void gemm_bt(
    const unsigned short* __restrict__ A,   // [M][K] bf16 row-major
    const unsigned short* __restrict__ BT,  // [N][K] bf16 row-major
    void* __restrict__ C,
    const float* __restrict__ bias,
    const float* __restrict__ cs,
    int M, int N, int K, int kChunk, int ldc) {
  constexpr int WTM = BM / 2, WTN = BN / 2;
  constexpr int MR = WTM / 16, NR = WTN / 16;
  constexpr int AIT = BM * 4 / 256;
  constexpr int BIT = BN * 4 / 256;

  __shared__ unsigned short As[BM * 32];
  __shared__ unsigned short Bs[BN * 32];

  const int t = threadIdx.x;
  const int lane = t & 63, wave = t >> 6;
  const int wr = wave >> 1, wc = wave & 1;
  const int bm = blockIdx.x, bn = blockIdx.y, bz = blockIdx.z;
  const int row0 = bm * BM, col0 = bn * BN;
  const int kbeg = bz * kChunk, kend = kbeg + kChunk;
  const int lrow = lane & 15;
  const int lk = (lane >> 4) * 8;

  f32x4 acc[MR][NR];
#pragma unroll
  for (int m = 0; m < MR; ++m)
#pragma unroll
    for (int n = 0; n < NR; ++n) acc[m][n] = (f32x4){0.f, 0.f, 0.f, 0.f};

  for (int k0 = kbeg; k0 < kend; k0 += 32) {
#pragma unroll
    for (int i = 0; i < AIT; ++i) {
      int flat = i * 256 + t;
      int r = flat >> 2, ko = (flat & 3) * 8;
      gload16(A + (size_t)(row0 + r) * K + k0 + ko, As + (size_t)flat * 8);
    }
#pragma unroll
    for (int i = 0; i < BIT; ++i) {
      int flat = i * 256 + t;
      int r = flat >> 2, ko = (flat & 3) * 8;
      gload16(BT + (size_t)(col0 + r) * K + k0 + ko, Bs + (size_t)flat * 8);
    }
    __syncthreads();

    bf16x8 af[MR], bfr[NR];
#pragma unroll
    for (int m = 0; m < MR; ++m)
      af[m] = *(const bf16x8*)&As[(wr * WTM + m * 16 + lrow) * 32 + lk];
#pragma unroll
    for (int n = 0; n < NR; ++n)
      bfr[n] = *(const bf16x8*)&Bs[(wc * WTN + n * 16 + lrow) * 32 + lk];
#pragma unroll
    for (int m = 0; m < MR; ++m)
#pragma unroll
      for (int n = 0; n < NR; ++n)
        acc[m][n] = __builtin_amdgcn_mfma_f32_16x16x32_bf16(af[m], bfr[n], acc[m][n], 0, 0, 0);
    __syncthreads();
  }

  const int r0 = row0 + wr * WTM, c0 = col0 + wc * WTN;
  if constexpr (EPI == 2) {
    float* Cf = (float*)C + (size_t)bz * M * ldc;
#pragma unroll
    for (int m = 0; m < MR; ++m)
#pragma unroll
      for (int n = 0; n < NR; ++n)
#pragma unroll
        for (int j = 0; j < 4; ++j) {
          int row = r0 + m * 16 + (lane >> 4) * 4 + j;
          int col = c0 + n * 16 + lrow;
          Cf[(size_t)row * ldc + col] = acc[m][n][j];
        }
  } else if constexpr (EPI == 4) {
    unsigned short* Cb = (unsigned short*)C + (size_t)bz * M * ldc;
#pragma unroll
    for (int m = 0; m < MR; ++m)
#pragma unroll
      for (int n = 0; n < NR; ++n)
#pragma unroll
        for (int j = 0; j < 4; ++j) {
          int row = r0 + m * 16 + (lane >> 4) * 4 + j;
          int col = c0 + n * 16 + lrow;
          Cb[(size_t)row * ldc + col] = f2bf(acc[m][n][j]);
        }
  } else {
    unsigned short* Cb = (unsigned short*)C;
#pragma unroll
    for (int m = 0; m < MR; ++m)
#pragma unroll
      for (int n = 0; n < NR; ++n)
#pragma unroll
        for (int j = 0; j < 4; ++j) {
          int row = r0 + m * 16 + (lane >> 4) * 4 + j;
          int col = c0 + n * 16 + lrow;
          float v = acc[m][n][j];
          if constexpr (EPI == 1) v = v > 0.f ? v : 0.f;
          if constexpr (EPI == 3) v = (v + bias[row]) * cs[col];
          Cb[(size_t)row * ldc + col] = f2bf(v);
        }
  }
}

// ---------- reduce bf16 split-K partials -> relu -> bf16 ----------
__global__ __launch_bounds__(256) void reduce_relu_b16p(const u16x4* __restrict__ part,
                                                        u16x4* __restrict__ out,
                                                        int total4, int splits) {
  const int stride = gridDim.x * 256;
  for (int i = blockIdx.x * 256 + threadIdx.x; i < total4; i += stride) {
    float s0 = 0.f, s1 = 0.f, s2 = 0.f, s3 = 0.f;
    for (int z = 0; z < splits; ++z) {
      u16x4 v = part[(size_t)z * total4 + i];
      s0 += bf2f(v[0]); s1 += bf2f(v[1]); s2 += bf2f(v[2]); s3 += bf2f(v[3]);
    }
    u16x4 o;
    o[0] = f2bf(s0 > 0.f ? s0 : 0.f);
    o[1] = f2bf(s1 > 0.f ? s1 : 0.f);
    o[2] = f2bf(s2 > 0.f ? s2 : 0.f);
    o[3] = f2bf(s3 > 0.f ? s3 : 0.f);
    out[i] = o;
  }
}

// ---------- reduce gemm3 f32 partials -> (s+b2[row])*sv[col] -> bf16 ZT[64][8192] ----------
__global__ __launch_bounds__(256) void reduce_zt(const float4* __restrict__ part,
                                                 const float* __restrict__ b2,
                                                 const float* __restrict__ sv,
                                                 u16x4* __restrict__ out) {
  const int i4 = blockIdx.x * 256 + threadIdx.x;  // over 64*8192/4 = 131072
  const int row = i4 >> 11;
  const int col0 = (i4 & 2047) * 4;
  float4 s = part[i4];
#pragma unroll
  for (int z = 1; z < 4; ++z) {
    float4 v = part[(size_t)z * 131072 + i4];
    s.x += v.x; s.y += v.y; s.z += v.z; s.w += v.w;
  }
  const float b = b2[row];
  u16x4 o;
  o[0] = f2bf((s.x + b) * sv[col0 + 0]);
  o[1] = f2bf((s.y + b) * sv[col0 + 1]);
  o[2] = f2bf((s.z + b) * sv[col0 + 2]);
  o[3] = f2bf((s.w + b) * sv[col0 + 3]);
  out[i4] = o;
}

// ---------- reduce gemm4 bf16 partials -> f32 out ----------
__global__ __launch_bounds__(256) void reduce_out(const u16x4* __restrict__ part,
                                                  float4* __restrict__ out,
                                                  int total4, int splits) {
  const int i = blockIdx.x * 256 + threadIdx.x;
  if (i >= total4) return;
  float s0 = 0.f, s1 = 0.f, s2 = 0.f, s3 = 0.f;
  for (int z = 0; z < splits; ++z) {
    u16x4 v = part[(size_t)z * total4 + i];
    s0 += bf2f(v[0]); s1 += bf2f(v[1]); s2 += bf2f(v[2]); s3 += bf2f(v[3]);
  }
  out[i] = (float4){s0, s1, s2, s3};
}

// ---------- launch ----------
extern "C" void kernel_launch(void* const* d_in, const int* in_sizes, int n_in,
                              void* d_out, int out_size, void* d_ws, size_t ws_size,
                              hipStream_t stream) {
  const float* X     = (const float*)d_in[0];
  const float* tilde = (const float*)d_in[1];
  const float* W1    = (const float*)d_in[2];
  const float* b1    = (const float*)d_in[3];
  const float* W2    = (const float*)d_in[4];
  const float* b2    = (const float*)d_in[5];
  float* out = (float*)d_out;

  constexpr int N = 8192, F = 1024, H = 512, Cc = 64;

  char* ws = (char*)d_ws;
  size_t off = 0;
  auto alloc = [&](size_t bytes) {
    char* p = ws + off;
    off += (bytes + 255) & ~(size_t)255;
    return p;
  };
  // persistent region
  unsigned short* Tbf  = (unsigned short*)alloc((size_t)N * N * 2);   // 128 MB
  unsigned short* XW1T = (unsigned short*)alloc((size_t)H * N * 2);   // 8 MB
  unsigned short* hbuf = (unsigned short*)alloc((size_t)N * H * 2);   // 8 MB
  unsigned short* ZT   = (unsigned short*)alloc((size_t)Cc * N * 2);  // 1 MB
  unsigned short* W2T  = (unsigned short*)alloc((size_t)Cc * H * 2);  // 64 KB
  float* partials2 = (float*)alloc(64 * N * 4);                       // 2 MB
  float* D2 = (float*)alloc(N * 4);
  float* sv = (float*)alloc(N * 4);
  // scratch zone (serial reuse):
  //  A: [Xbf 16MB | W1T 2MB pad | partials 32MB]
  //  B: part2 bf16 32MB   C: part3 f32 8MB   D: part4 bf16 16MB
  const size_t scratch_base = off;
  unsigned short* Xbf = (unsigned short*)(ws + scratch_base);                      // 16 MB
  unsigned short* W1T = (unsigned short*)(ws + scratch_base + (size_t)N * F * 2);  // 1 MB
  float* partials = (float*)(ws + scratch_base + (size_t)N * F * 2 + 0x200000);    // 32 MB
  unsigned short* part2 = (unsigned short*)(ws + scratch_base);  // 4*8192*512*2 = 32 MB
  float* part3 = (float*)(ws + scratch_base);                    // 4*64*8192*4  = 8 MB
  unsigned short* part4 = (unsigned short*)(ws + scratch_base);  // 16*8192*64*2 = 16 MB

  const size_t need_split = scratch_base + (size_t)N * F * 2 + 0x200000 + (size_t)1024 * N * 4;
  const bool splitk = ws_size >= need_split;

  // fused sums + tilde->bf16 (A never materialized; scale folded into epilogues)
  sums_convert<<<1024, 256, 0, stream>>>(tilde, (float4*)partials, D2, (u16x4*)Tbf);
  zreduce<<<dim3(8, 64), 256, 0, stream>>>((const float4*)partials, (float4*)partials2);
  colscale_kernel<<<N / 256, 256, 0, stream>>>(partials2, D2, sv);

  // operand prep
  convert_bf16<<<2048, 256, 0, stream>>>((const float4*)X, (u16x4*)Xbf, N * F / 4);
  transpose_cvt<<<(F * H) / 256, 256, 0, stream>>>(W1, W1T, F, H);
  transpose_cvt<<<(H * Cc) / 256, 256, 0, stream>>>(W2, W2T, H, Cc);

  // gemm1: XW1T[H][N] = W1T[H][F] @ X^T, epi: (acc+b1[row])*s[col]
  // BM=64 -> grid 8x64 = 512 blocks (2/CU) for latency overlap
  gemm_bt<64, 128, 3><<<dim3(H / 64, N / 128, 1), 256, 0, stream>>>(
      W1T, Xbf, XW1T, b1, sv, H, N, F, F, N);

  if (splitk) {
    // gemm2: h[N][H] = tilde_bf @ (s*XW1), split-K=4, bf16 partials
    gemm_bt<128, 128, 4><<<dim3(N / 128, H / 128, 4), 256, 0, stream>>>(
        Tbf, XW1T, part2, nullptr, nullptr, N, H, N, N / 4, H);
    reduce_relu_b16p<<<1024, 256, 0, stream>>>((const u16x4*)part2, (u16x4*)hbuf,
                                               N * H / 4, 4);
    // gemm3: ZT[C][N] = W2T[C][H] @ h^T, split-K=4, f32 partials; epi in reduce_zt
    gemm_bt<64, 128, 2><<<dim3(1, N / 128, 4), 256, 0, stream>>>(
        W2T, hbuf, part3, nullptr, nullptr, Cc, N, H, H / 4, N);
    reduce_zt<<<(Cc * N / 4) / 256, 256, 0, stream>>>((const float4*)part3, b2, sv,
                                                      (u16x4*)ZT);
    // gemm4: out[N][C] = tilde_bf @ (s*Z), split-K=16, bf16 partials
    gemm_bt<128, 64, 4><<<dim3(N / 128, 1, 16), 256, 0, stream>>>(
        Tbf, ZT, part4, nullptr, nullptr, N, Cc, N, N / 16, Cc);
    reduce_out<<<(N * Cc / 4) / 256, 256, 0, stream>>>((const u16x4*)part4, (float4*)out,
                                                       N * Cc / 4, 16);
  } else {
    gemm_bt<128, 128, 1><<<dim3(N / 128, H / 128, 1), 256, 0, stream>>>(
        Tbf, XW1T, hbuf, nullptr, nullptr, N, H, N, N, H);
    gemm_bt<64, 128, 3><<<dim3(1, N / 128, 1), 256, 0, stream>>>(
        W2T, hbuf, ZT, b2, sv, Cc, N, H, H, N);
    gemm_bt<128, 64, 4><<<dim3(N / 128, 1, 1), 256, 0, stream>>>(
        Tbf, ZT, part4, nullptr, nullptr, N, Cc, N, N, Cc);
    reduce_out<<<(N * Cc / 4) / 256, 256, 0, stream>>>((const u16x4*)part4, (float4*)out,
                                                       N * Cc / 4, 1);
  }
}

// Round 7
// 270.430 us; speedup vs baseline: 1.8283x; 1.2357x over previous
//
#include <hip/hip_runtime.h>
#include <hip/hip_bf16.h>
#include <cstdint>
#include <cstddef>

// ---------- types ----------
typedef __attribute__((ext_vector_type(8))) __bf16 bf16x8;
typedef __attribute__((ext_vector_type(4))) float f32x4;
typedef __attribute__((ext_vector_type(4))) unsigned short u16x4;

#define DEVINL static __device__ __forceinline__

DEVINL unsigned short f2bf(float x) {
  union { float f; unsigned u; } un; un.f = x;
  unsigned r = un.u + 0x7fffu + ((un.u >> 16) & 1u);
  return (unsigned short)(r >> 16);
}

DEVINL float bf2f(unsigned short b) {
  union { unsigned u; float f; } un; un.u = ((unsigned)b) << 16;
  return un.f;
}

DEVINL void gload16(const void* g, void* l) {
  __builtin_amdgcn_global_load_lds(
      (__attribute__((address_space(1))) void*)(void*)(uintptr_t)(const void*)g,
      (__attribute__((address_space(3))) void*)l, 16, 0, 0);
}

#define SBAR() asm volatile("s_barrier" ::: "memory")
#define WLG0() asm volatile("s_waitcnt lgkmcnt(0)" ::: "memory")
#define WVM6() asm volatile("s_waitcnt vmcnt(6)" ::: "memory")

// ---------- fused: sums of tilde + convert tilde -> bf16. NO ATOMICS. ----------
__global__ __launch_bounds__(256, 4) void sums_convert(const float* __restrict__ tilde,
                                                       float4* __restrict__ partials4,
                                                       float* __restrict__ D2,
                                                       u16x4* __restrict__ Tbf) {
  const int t = threadIdx.x;
  float4 ca[8];
#pragma unroll
  for (int i = 0; i < 8; ++i) ca[i] = (float4){0.f, 0.f, 0.f, 0.f};
  float rs[8];
#pragma unroll
  for (int r = 0; r < 8; ++r) rs[r] = 0.f;

  const int base_row = blockIdx.x * 8;
#pragma unroll
  for (int r = 0; r < 8; ++r) {
    const size_t rowoff = (size_t)(base_row + r) * 2048;  // float4 units
    const float4* rp = (const float4*)tilde + rowoff;
    u16x4* op = Tbf + rowoff;
#pragma unroll
    for (int i = 0; i < 8; ++i) {
      float4 v = rp[t + i * 256];
      ca[i].x += v.x; ca[i].y += v.y; ca[i].z += v.z; ca[i].w += v.w;
      rs[r] += (v.x + v.y) + (v.z + v.w);
      u16x4 o;
      o[0] = f2bf(v.x); o[1] = f2bf(v.y); o[2] = f2bf(v.z); o[3] = f2bf(v.w);
      op[t + i * 256] = o;
    }
  }
  float4* pb = partials4 + (size_t)blockIdx.x * 2048;
#pragma unroll
  for (int i = 0; i < 8; ++i) pb[t + i * 256] = ca[i];

#pragma unroll
  for (int r = 0; r < 8; ++r) {
#pragma unroll
    for (int off = 32; off > 0; off >>= 1) rs[r] += __shfl_down(rs[r], off, 64);
  }
  __shared__ float wsum[4][8];
  const int wave = t >> 6;
  if ((t & 63) == 0) {
#pragma unroll
    for (int r = 0; r < 8; ++r) wsum[wave][r] = rs[r];
  }
  __syncthreads();
  if (t < 8) D2[base_row + t] = wsum[0][t] + wsum[1][t] + wsum[2][t] + wsum[3][t];
}

// ---------- reduce partials over z-chunks: partials[1024][8192] -> partials2[64][8192] ----------
__global__ __launch_bounds__(256) void zreduce(const float4* __restrict__ partials4,
                                               float4* __restrict__ partials2_4) {
  const int c4 = blockIdx.x * 256 + threadIdx.x;
  const int z0 = blockIdx.y * 16;
  float4 s = (float4){0.f, 0.f, 0.f, 0.f};
#pragma unroll 4
  for (int z = z0; z < z0 + 16; ++z) {
    float4 v = partials4[(size_t)z * 2048 + c4];
    s.x += v.x; s.y += v.y; s.z += v.z; s.w += v.w;
  }
  partials2_4[(size_t)blockIdx.y * 2048 + c4] = s;
}

// ---------- sv[j] = sqrt(colsum[j] * D2[j]) ----------
__global__ __launch_bounds__(256) void colscale_kernel(const float* __restrict__ partials2,
                                                       const float* __restrict__ D2,
                                                       float* __restrict__ sv) {
  int j = blockIdx.x * 256 + threadIdx.x;
  float d1 = 0.f;
  for (int z = 0; z < 64; ++z) d1 += partials2[z * 8192 + j];
  sv[j] = sqrtf(d1 * D2[j]);
}

// ---------- fp32 -> bf16 convert ----------
__global__ __launch_bounds__(256) void convert_bf16(const float4* __restrict__ in,
                                                    u16x4* __restrict__ out, int n4) {
  const int stride = gridDim.x * 256;
  for (int i = blockIdx.x * 256 + threadIdx.x; i < n4; i += stride) {
    float4 v = in[i];
    u16x4 o;
    o[0] = f2bf(v.x); o[1] = f2bf(v.y); o[2] = f2bf(v.z); o[3] = f2bf(v.w);
    out[i] = o;
  }
}

// ---------- transpose + convert: out[c][r] = bf16(in[r][c]) ----------
__global__ __launch_bounds__(256) void transpose_cvt(const float* __restrict__ in,
                                                     unsigned short* __restrict__ out,
                                                     int R, int C) {
  int o = blockIdx.x * 256 + threadIdx.x;
  if (o >= R * C) return;
  int c = o / R, r = o - c * R;
  out[o] = f2bf(in[(size_t)r * C + c]);
}

// ================= 8-phase 256x256 GEMM for gemm2 =================
// C_part[z][8192][512] (bf16) += tile of Tbf[8192][8192] @ XW1.
// BT = XW1T [512][8192]. BK=64, 8 waves (2Mx4N), 128KB LDS, split-K=4.
// T2 swizzle: linear LDS dest for global_load_lds, inverse-swizzled global
// source, XOR(bits9,10 -> bits5,6) on ds_read. Row-permuted halves so each
// staged half-tile == one consumption region.
__global__ __launch_bounds__(512, 2) void gemm2_8ph(
    const unsigned short* __restrict__ A,   // Tbf [8192][8192] bf16
    const unsigned short* __restrict__ BT,  // XW1T [512][8192] bf16
    unsigned short* __restrict__ Cpart) {   // [4][8192][512] bf16 partials
  constexpr int K = 8192;
  constexpr int LDC = 512;
  constexpr int NT = 32;  // K-tiles of 64 per block (kChunk = 2048)

  __shared__ __align__(16) char lds[131072];  // [buf][A 32K | B 32K]

  const int tid = threadIdx.x;
  const int lane = tid & 63, w = tid >> 6;
  const int wr = w >> 2, wc = w & 3;          // 2 x 4 wave grid
  const int lrow = lane & 15, slot = lane >> 4;
  const int xorv = (((lrow >> 2) & 1) << 5) | (((lrow >> 3) & 1) << 6);
  const int row0 = blockIdx.x * 256;
  const int col0 = blockIdx.y * 256;
  const size_t kbeg = (size_t)blockIdx.z * 2048;

  f32x4 acc[8][4];
#pragma unroll
  for (int m = 0; m < 8; ++m)
#pragma unroll
    for (int n = 0; n < 4; ++n) acc[m][n] = (f32x4){0.f, 0.f, 0.f, 0.f};
  bf16x8 a[4][2], b[4][2];

  // stage half-tile h of K-tile tk into buffer buf (2 x 8KB issues, 512 thr)
  auto STAGE_A = [&](int buf, int h, int tk) {
    if (tk >= NT) return;
    const size_t kabs = kbeg + (size_t)tk * 64;
    char* dst = lds + buf * 65536;
#pragma unroll
    for (int j = 0; j < 2; ++j) {
      int L = h * 16384 + (j * 512 + tid) * 16;
      int y = L ^ ((L & 0x600) >> 4);
      int lam = y >> 7, cb = y & 127;
      int R = ((lam >> 6) & 1) * 128 + (lam >> 7) * 64 + (lam & 63);
      gload16((const char*)A + ((size_t)(row0 + R) * K + kabs) * 2 + cb, dst + L);
    }
  };
  auto STAGE_B = [&](int buf, int h, int tk) {
    if (tk >= NT) return;
    const size_t kabs = kbeg + (size_t)tk * 64;
    char* dst = lds + buf * 65536 + 32768;
#pragma unroll
    for (int j = 0; j < 2; ++j) {
      int L = h * 16384 + (j * 512 + tid) * 16;
      int y = L ^ ((L & 0x600) >> 4);
      int lam = y >> 7, cb = y & 127;
      int R = ((lam >> 5) & 3) * 64 + (lam >> 7) * 32 + (lam & 31);
      gload16((const char*)BT + ((size_t)(col0 + R) * K + kabs) * 2 + cb, dst + L);
    }
  };
  auto LDA = [&](int buf, int mh) {
    const char* base = lds + buf * 65536;
#pragma unroll
    for (int mm = 0; mm < 4; ++mm)
#pragma unroll
      for (int ks = 0; ks < 2; ++ks) {
        int lin = mh * 16384 + wr * 8192 + mm * 2048 + lrow * 128 + ks * 64 + slot * 16;
        a[mm][ks] = *(const bf16x8*)(base + (lin ^ xorv));
      }
  };
  auto LDB = [&](int buf, int nh) {
    const char* base = lds + buf * 65536 + 32768;
#pragma unroll
    for (int nn = 0; nn < 2; ++nn)
#pragma unroll
      for (int ks = 0; ks < 2; ++ks) {
        int lin = nh * 16384 + wc * 4096 + nn * 2048 + lrow * 128 + ks * 64 + slot * 16;
        b[nh * 2 + nn][ks] = *(const bf16x8*)(base + (lin ^ xorv));
      }
  };
  auto MMA = [&](int mh, int nh) {
    __builtin_amdgcn_s_setprio(1);
#pragma unroll
    for (int mm = 0; mm < 4; ++mm)
#pragma unroll
      for (int nn = 0; nn < 2; ++nn)
#pragma unroll
        for (int ks = 0; ks < 2; ++ks)
          acc[mh * 4 + mm][nh * 2 + nn] = __builtin_amdgcn_mfma_f32_16x16x32_bf16(
              a[mm][ks], b[nh * 2 + nn][ks], acc[mh * 4 + mm][nh * 2 + nn], 0, 0, 0);
    __builtin_amdgcn_s_setprio(0);
  };

  // prologue: tile0 fully + tile1 {A0,B0,B1}; vmcnt(6) leaves tile1's 3 newest
  STAGE_A(0, 0, 0); STAGE_B(0, 0, 0); STAGE_B(0, 1, 0); STAGE_A(0, 1, 0);
  STAGE_A(1, 0, 1); STAGE_B(1, 0, 1); STAGE_B(1, 1, 1);
  WVM6(); SBAR();

  for (int it = 0; it < NT / 2; ++it) {
    const int t = 2 * it;
    // ph0: quadrant (mh0,nh0) of tile t; stage (t+1).A1 -> buf1
    LDA(0, 0); LDB(0, 0);
    STAGE_A(1, 1, t + 1);
    SBAR(); WLG0();
    MMA(0, 0);
    SBAR();
    // ph1: (mh0,nh1); stage (t+2).A0 -> buf0
    LDB(0, 1);
    STAGE_A(0, 0, t + 2);
    SBAR(); WLG0();
    MMA(0, 1);
    SBAR();
    // ph2: (mh1,nh1); stage (t+2).B0
    LDA(0, 1);
    STAGE_B(0, 0, t + 2);
    SBAR(); WLG0();
    MMA(1, 1);
    SBAR();
    // ph3: (mh1,nh0) from regs; stage (t+2).B1; counted vmcnt
    STAGE_B(0, 1, t + 2);
    WVM6();
    SBAR();
    MMA(1, 0);
    SBAR();
    // ph4: tile t+1 (buf1) (mh0,nh0); stage (t+2).A1
    LDA(1, 0); LDB(1, 0);
    STAGE_A(0, 1, t + 2);
    SBAR(); WLG0();
    MMA(0, 0);
    SBAR();
    // ph5: (mh0,nh1); stage (t+3).A0 -> buf1
    LDB(1, 1);
    STAGE_A(1, 0, t + 3);
    SBAR(); WLG0();
    MMA(0, 1);
    SBAR();
    // ph6: (mh1,nh1); stage (t+3).B0
    LDA(1, 1);
    STAGE_B(1, 0, t + 3);
    SBAR(); WLG0();
    MMA(1, 1);
    SBAR();
    // ph7: (mh1,nh0) from regs; stage (t+3).B1; counted vmcnt
    STAGE_B(1, 1, t + 3);
    WVM6();
    SBAR();
    MMA(1, 0);
    SBAR();
  }

  // epilogue: bf16 partial write
  unsigned short* Cb = Cpart + (size_t)blockIdx.z * 8192 * LDC;
  const int r0 = row0 + wr * 128, c0 = col0 + wc * 64;
#pragma unroll
  for (int m = 0; m < 8; ++m)
#pragma unroll
    for (int n = 0; n < 4; ++n)
#pragma unroll
      for (int j = 0; j < 4; ++j) {
        int row = r0 + m * 16 + (lane >> 4) * 4 + j;
        int col = c0 + n * 16 + lrow;
        Cb[(size_t)row * LDC + col] = f2bf(acc[m][n][j]);
      }
}

// ---------- tiled MFMA GEMM: C[M,N] = A[M,K] @ B[K,N], BT given as [N][K] ----------
// EPI: 1 = bf16 out + relu; 2 = f32 partial (split-K); 3 = bf16 out, (acc+bias[row])*cs[col];
//      4 = bf16 partial (split-K)
template <int BM, int BN, int EPI>
__global__ __launch_bounds__(256) void gemm_bt(
    const unsigned short* __restrict__ A,   // [M][K] bf16 row-major
    const unsigned short* __restrict__ BT,  // [N][K] bf16 row-major
    void* __restrict__ C,
    const float* __restrict__ bias,
    const float* __restrict__ cs,
    int M, int N, int K, int kChunk, int ldc) {
  constexpr int WTM = BM / 2, WTN = BN / 2;
  constexpr int MR = WTM / 16, NR = WTN / 16;
  constexpr int AIT = BM * 4 / 256;
  constexpr int BIT = BN * 4 / 256;

  __shared__ unsigned short As[BM * 32];
  __shared__ unsigned short Bs[BN * 32];

  const int t = threadIdx.x;
  const int lane = t & 63, wave = t >> 6;
  const int wr = wave >> 1, wc = wave & 1;
  const int bm = blockIdx.x, bn = blockIdx.y, bz = blockIdx.z;
  const int row0 = bm * BM, col0 = bn * BN;
  const int kbeg = bz * kChunk, kend = kbeg + kChunk;
  const int lrow = lane & 15;
  const int lk = (lane >> 4) * 8;

  f32x4 acc[MR][NR];
#pragma unroll
  for (int m = 0; m < MR; ++m)
#pragma unroll
    for (int n = 0; n < NR; ++n) acc[m][n] = (f32x4){0.f, 0.f, 0.f, 0.f};

  for (int k0 = kbeg; k0 < kend; k0 += 32) {
#pragma unroll
    for (int i = 0; i < AIT; ++i) {
      int flat = i * 256 + t;
      int r = flat >> 2, ko = (flat & 3) * 8;
      gload16(A + (size_t)(row0 + r) * K + k0 + ko, As + (size_t)flat * 8);
    }
#pragma unroll
    for (int i = 0; i < BIT; ++i) {
      int flat = i * 256 + t;
      int r = flat >> 2, ko = (flat & 3) * 8;
      gload16(BT + (size_t)(col0 + r) * K + k0 + ko, Bs + (size_t)flat * 8);
    }
    __syncthreads();

    bf16x8 af[MR], bfr[NR];
#pragma unroll
    for (int m = 0; m < MR; ++m)
      af[m] = *(const bf16x8*)&As[(wr * WTM + m * 16 + lrow) * 32 + lk];
#pragma unroll
    for (int n = 0; n < NR; ++n)
      bfr[n] = *(const bf16x8*)&Bs[(wc * WTN + n * 16 + lrow) * 32 + lk];
#pragma unroll
    for (int m = 0; m < MR; ++m)
#pragma unroll
      for (int n = 0; n < NR; ++n)
        acc[m][n] = __builtin_amdgcn_mfma_f32_16x16x32_bf16(af[m], bfr[n], acc[m][n], 0, 0, 0);
    __syncthreads();
  }

  const int r0 = row0 + wr * WTM, c0 = col0 + wc * WTN;
  if constexpr (EPI == 2) {
    float* Cf = (float*)C + (size_t)bz * M * ldc;
#pragma unroll
    for (int m = 0; m < MR; ++m)
#pragma unroll
      for (int n = 0; n < NR; ++n)
#pragma unroll
        for (int j = 0; j < 4; ++j) {
          int row = r0 + m * 16 + (lane >> 4) * 4 + j;
          int col = c0 + n * 16 + lrow;
          Cf[(size_t)row * ldc + col] = acc[m][n][j];
        }
  } else if constexpr (EPI == 4) {
    unsigned short* Cb = (unsigned short*)C + (size_t)bz * M * ldc;
#pragma unroll
    for (int m = 0; m < MR; ++m)
#pragma unroll
      for (int n = 0; n < NR; ++n)
#pragma unroll
        for (int j = 0; j < 4; ++j) {
          int row = r0 + m * 16 + (lane >> 4) * 4 + j;
          int col = c0 + n * 16 + lrow;
          Cb[(size_t)row * ldc + col] = f2bf(acc[m][n][j]);
        }
  } else {
    unsigned short* Cb = (unsigned short*)C;
#pragma unroll
    for (int m = 0; m < MR; ++m)
#pragma unroll
      for (int n = 0; n < NR; ++n)
#pragma unroll
        for (int j = 0; j < 4; ++j) {
          int row = r0 + m * 16 + (lane >> 4) * 4 + j;
          int col = c0 + n * 16 + lrow;
          float v = acc[m][n][j];
          if constexpr (EPI == 1) v = v > 0.f ? v : 0.f;
          if constexpr (EPI == 3) v = (v + bias[row]) * cs[col];
          Cb[(size_t)row * ldc + col] = f2bf(v);
        }
  }
}

// ---------- reduce bf16 split-K partials -> relu -> bf16 ----------
__global__ __launch_bounds__(256) void reduce_relu_b16p(const u16x4* __restrict__ part,
                                                        u16x4* __restrict__ out,
                                                        int total4, int splits) {
  const int stride = gridDim.x * 256;
  for (int i = blockIdx.x * 256 + threadIdx.x; i < total4; i += stride) {
    float s0 = 0.f, s1 = 0.f, s2 = 0.f, s3 = 0.f;
    for (int z = 0; z < splits; ++z) {
      u16x4 v = part[(size_t)z * total4 + i];
      s0 += bf2f(v[0]); s1 += bf2f(v[1]); s2 += bf2f(v[2]); s3 += bf2f(v[3]);
    }
    u16x4 o;
    o[0] = f2bf(s0 > 0.f ? s0 : 0.f);
    o[1] = f2bf(s1 > 0.f ? s1 : 0.f);
    o[2] = f2bf(s2 > 0.f ? s2 : 0.f);
    o[3] = f2bf(s3 > 0.f ? s3 : 0.f);
    out[i] = o;
  }
}

// ---------- reduce gemm3 f32 partials -> (s+b2[row])*sv[col] -> bf16 ZT[64][8192] ----------
__global__ __launch_bounds__(256) void reduce_zt(const float4* __restrict__ part,
                                                 const float* __restrict__ b2,
                                                 const float* __restrict__ sv,
                                                 u16x4* __restrict__ out) {
  const int i4 = blockIdx.x * 256 + threadIdx.x;  // over 64*8192/4 = 131072
  const int row = i4 >> 11;
  const int col0 = (i4 & 2047) * 4;
  float4 s = part[i4];
#pragma unroll
  for (int z = 1; z < 4; ++z) {
    float4 v = part[(size_t)z * 131072 + i4];
    s.x += v.x; s.y += v.y; s.z += v.z; s.w += v.w;
  }
  const float b = b2[row];
  u16x4 o;
  o[0] = f2bf((s.x + b) * sv[col0 + 0]);
  o[1] = f2bf((s.y + b) * sv[col0 + 1]);
  o[2] = f2bf((s.z + b) * sv[col0 + 2]);
  o[3] = f2bf((s.w + b) * sv[col0 + 3]);
  out[i4] = o;
}

// ---------- reduce gemm4 bf16 partials -> f32 out ----------
__global__ __launch_bounds__(256) void reduce_out(const u16x4* __restrict__ part,
                                                  float4* __restrict__ out,
                                                  int total4, int splits) {
  const int i = blockIdx.x * 256 + threadIdx.x;
  if (i >= total4) return;
  float s0 = 0.f, s1 = 0.f, s2 = 0.f, s3 = 0.f;
  for (int z = 0; z < splits; ++z) {
    u16x4 v = part[(size_t)z * total4 + i];
    s0 += bf2f(v[0]); s1 += bf2f(v[1]); s2 += bf2f(v[2]); s3 += bf2f(v[3]);
  }
  out[i] = (float4){s0, s1, s2, s3};
}

// ---------- launch ----------
extern "C" void kernel_launch(void* const* d_in, const int* in_sizes, int n_in,
                              void* d_out, int out_size, void* d_ws, size_t ws_size,
                              hipStream_t stream) {
  const float* X     = (const float*)d_in[0];
  const float* tilde = (const float*)d_in[1];
  const float* W1    = (const float*)d_in[2];
  const float* b1    = (const float*)d_in[3];
  const float* W2    = (const float*)d_in[4];
  const float* b2    = (const float*)d_in[5];
  float* out = (float*)d_out;

  constexpr int N = 8192, F = 1024, H = 512, Cc = 64;

  char* ws = (char*)d_ws;
  size_t off = 0;
  auto alloc = [&](size_t bytes) {
    char* p = ws + off;
    off += (bytes + 255) & ~(size_t)255;
    return p;
  };
  // persistent region
  unsigned short* Tbf  = (unsigned short*)alloc((size_t)N * N * 2);   // 128 MB
  unsigned short* XW1T = (unsigned short*)alloc((size_t)H * N * 2);   // 8 MB
  unsigned short* hbuf = (unsigned short*)alloc((size_t)N * H * 2);   // 8 MB
  unsigned short* ZT   = (unsigned short*)alloc((size_t)Cc * N * 2);  // 1 MB
  unsigned short* W2T  = (unsigned short*)alloc((size_t)Cc * H * 2);  // 64 KB
  float* partials2 = (float*)alloc(64 * N * 4);                       // 2 MB
  float* D2 = (float*)alloc(N * 4);
  float* sv = (float*)alloc(N * 4);
  // scratch zone (serial reuse):
  //  A: [Xbf 16MB | W1T 2MB pad | partials 32MB]
  //  B: part2 bf16 32MB   C: part3 f32 8MB   D: part4 bf16 16MB
  const size_t scratch_base = off;
  unsigned short* Xbf = (unsigned short*)(ws + scratch_base);                      // 16 MB
  unsigned short* W1T = (unsigned short*)(ws + scratch_base + (size_t)N * F * 2);  // 1 MB
  float* partials = (float*)(ws + scratch_base + (size_t)N * F * 2 + 0x200000);    // 32 MB
  unsigned short* part2 = (unsigned short*)(ws + scratch_base);  // 4*8192*512*2 = 32 MB
  float* part3 = (float*)(ws + scratch_base);                    // 4*64*8192*4  = 8 MB
  unsigned short* part4 = (unsigned short*)(ws + scratch_base);  // 16*8192*64*2 = 16 MB

  const size_t need_split = scratch_base + (size_t)N * F * 2 + 0x200000 + (size_t)1024 * N * 4;
  const bool splitk = ws_size >= need_split;

  // fused sums + tilde->bf16 (A never materialized; scale folded into epilogues)
  sums_convert<<<1024, 256, 0, stream>>>(tilde, (float4*)partials, D2, (u16x4*)Tbf);
  zreduce<<<dim3(8, 64), 256, 0, stream>>>((const float4*)partials, (float4*)partials2);
  colscale_kernel<<<N / 256, 256, 0, stream>>>(partials2, D2, sv);

  // operand prep
  convert_bf16<<<2048, 256, 0, stream>>>((const float4*)X, (u16x4*)Xbf, N * F / 4);
  transpose_cvt<<<(F * H) / 256, 256, 0, stream>>>(W1, W1T, F, H);
  transpose_cvt<<<(H * Cc) / 256, 256, 0, stream>>>(W2, W2T, H, Cc);

  // gemm1: XW1T[H][N] = W1T[H][F] @ X^T, epi: (acc+b1[row])*s[col]
  gemm_bt<64, 128, 3><<<dim3(H / 64, N / 128, 1), 256, 0, stream>>>(
      W1T, Xbf, XW1T, b1, sv, H, N, F, F, N);

  if (splitk) {
    // gemm2: 8-phase 256x256, split-K=4, bf16 partials
    gemm2_8ph<<<dim3(N / 256, H / 256, 4), 512, 0, stream>>>(Tbf, XW1T, part2);
    reduce_relu_b16p<<<1024, 256, 0, stream>>>((const u16x4*)part2, (u16x4*)hbuf,
                                               N * H / 4, 4);
    // gemm3: ZT[C][N] = W2T[C][H] @ h^T, split-K=4, f32 partials; epi in reduce_zt
    gemm_bt<64, 128, 2><<<dim3(1, N / 128, 4), 256, 0, stream>>>(
        W2T, hbuf, part3, nullptr, nullptr, Cc, N, H, H / 4, N);
    reduce_zt<<<(Cc * N / 4) / 256, 256, 0, stream>>>((const float4*)part3, b2, sv,
                                                      (u16x4*)ZT);
    // gemm4: out[N][C] = tilde_bf @ (s*Z), split-K=16, bf16 partials
    gemm_bt<128, 64, 4><<<dim3(N / 128, 1, 16), 256, 0, stream>>>(
        Tbf, ZT, part4, nullptr, nullptr, N, Cc, N, N / 16, Cc);
    reduce_out<<<(N * Cc / 4) / 256, 256, 0, stream>>>((const u16x4*)part4, (float4*)out,
                                                       N * Cc / 4, 16);
  } else {
    gemm_bt<128, 128, 1><<<dim3(N / 128, H / 128, 1), 256, 0, stream>>>(
        Tbf, XW1T, hbuf, nullptr, nullptr, N, H, N, N, H);
    gemm_bt<64, 128, 3><<<dim3(1, N / 128, 1), 256, 0, stream>>>(
        W2T, hbuf, ZT, b2, sv, Cc, N, H, H, N);
    gemm_bt<128, 64, 4><<<dim3(N / 128, 1, 1), 256, 0, stream>>>(
        Tbf, ZT, part4, nullptr, nullptr, N, Cc, N, N, Cc);
    reduce_out<<<(N * Cc / 4) / 256, 256, 0, stream>>>((const u16x4*)part4, (float4*)out,
                                                       N * Cc / 4, 1);
  }
}

// Round 8
// 259.851 us; speedup vs baseline: 1.9027x; 1.0407x over previous
//
#include <hip/hip_runtime.h>
#include <hip/hip_bf16.h>
#include <cstdint>
#include <cstddef>

// ---------- types ----------
typedef __attribute__((ext_vector_type(8))) __bf16 bf16x8;
typedef __attribute__((ext_vector_type(4))) float f32x4;
typedef __attribute__((ext_vector_type(4))) unsigned short u16x4;

#define DEVINL static __device__ __forceinline__

DEVINL unsigned short f2bf(float x) {
  union { float f; unsigned u; } un; un.f = x;
  unsigned r = un.u + 0x7fffu + ((un.u >> 16) & 1u);
  return (unsigned short)(r >> 16);
}

DEVINL float bf2f(unsigned short b) {
  union { unsigned u; float f; } un; un.u = ((unsigned)b) << 16;
  return un.f;
}

DEVINL void gload16(const void* g, void* l) {
  __builtin_amdgcn_global_load_lds(
      (__attribute__((address_space(1))) void*)(void*)(uintptr_t)(const void*)g,
      (__attribute__((address_space(3))) void*)l, 16, 0, 0);
}

#define SBAR() asm volatile("s_barrier" ::: "memory")
#define WLG0() asm volatile("s_waitcnt lgkmcnt(0)" ::: "memory")
#define WVM6() asm volatile("s_waitcnt vmcnt(6)" ::: "memory")

// ---------- fused: sums of tilde + convert tilde -> bf16. NO ATOMICS. ----------
// 512 blocks x 16 rows (2 blocks/CU, 8 waves/CU ~64KB in flight); partials 16 MB.
__global__ __launch_bounds__(256, 2) void sums_convert(const float* __restrict__ tilde,
                                                       float4* __restrict__ partials4,
                                                       float* __restrict__ D2,
                                                       u16x4* __restrict__ Tbf) {
  const int t = threadIdx.x;
  float4 ca[8];
#pragma unroll
  for (int i = 0; i < 8; ++i) ca[i] = (float4){0.f, 0.f, 0.f, 0.f};
  float rs[16];
#pragma unroll
  for (int r = 0; r < 16; ++r) rs[r] = 0.f;

  const int base_row = blockIdx.x * 16;
  for (int r = 0; r < 16; ++r) {
    const size_t rowoff = (size_t)(base_row + r) * 2048;  // float4 units
    const float4* rp = (const float4*)tilde + rowoff;
    u16x4* op = Tbf + rowoff;
#pragma unroll
    for (int i = 0; i < 8; ++i) {
      float4 v = rp[t + i * 256];
      ca[i].x += v.x; ca[i].y += v.y; ca[i].z += v.z; ca[i].w += v.w;
      rs[r] += (v.x + v.y) + (v.z + v.w);
      u16x4 o;
      o[0] = f2bf(v.x); o[1] = f2bf(v.y); o[2] = f2bf(v.z); o[3] = f2bf(v.w);
      op[t + i * 256] = o;
    }
  }
  float4* pb = partials4 + (size_t)blockIdx.x * 2048;
#pragma unroll
  for (int i = 0; i < 8; ++i) pb[t + i * 256] = ca[i];

#pragma unroll
  for (int r = 0; r < 16; ++r) {
#pragma unroll
    for (int off = 32; off > 0; off >>= 1) rs[r] += __shfl_down(rs[r], off, 64);
  }
  __shared__ float wsum[4][16];
  const int wave = t >> 6;
  if ((t & 63) == 0) {
#pragma unroll
    for (int r = 0; r < 16; ++r) wsum[wave][r] = rs[r];
  }
  __syncthreads();
  if (t < 16) D2[base_row + t] = wsum[0][t] + wsum[1][t] + wsum[2][t] + wsum[3][t];
}

// ---------- reduce partials over z-chunks: partials[512][8192] -> partials2[64][8192] ----------
__global__ __launch_bounds__(256) void zreduce(const float4* __restrict__ partials4,
                                               float4* __restrict__ partials2_4) {
  const int c4 = blockIdx.x * 256 + threadIdx.x;
  const int z0 = blockIdx.y * 8;
  float4 s = (float4){0.f, 0.f, 0.f, 0.f};
#pragma unroll
  for (int z = z0; z < z0 + 8; ++z) {
    float4 v = partials4[(size_t)z * 2048 + c4];
    s.x += v.x; s.y += v.y; s.z += v.z; s.w += v.w;
  }
  partials2_4[(size_t)blockIdx.y * 2048 + c4] = s;
}

// ---------- sv[j] = sqrt(colsum[j] * D2[j]) ----------
__global__ __launch_bounds__(256) void colscale_kernel(const float* __restrict__ partials2,
                                                       const float* __restrict__ D2,
                                                       float* __restrict__ sv) {
  int j = blockIdx.x * 256 + threadIdx.x;
  float d1 = 0.f;
  for (int z = 0; z < 64; ++z) d1 += partials2[z * 8192 + j];
  sv[j] = sqrtf(d1 * D2[j]);
}

// ---------- fused operand prep: X->bf16 | W1^T->bf16 | W2^T->bf16 (one launch) ----------
__global__ __launch_bounds__(256) void prep_fused(const float4* __restrict__ X4,
                                                  u16x4* __restrict__ Xbf4,
                                                  const float* __restrict__ W1,
                                                  unsigned short* __restrict__ W1T,
                                                  const float* __restrict__ W2,
                                                  unsigned short* __restrict__ W2T) {
  const int b = blockIdx.x;
  if (b < 2048) {
    const int n4 = 8192 * 1024 / 4;
    for (int i = b * 256 + threadIdx.x; i < n4; i += 2048 * 256) {
      float4 v = X4[i];
      u16x4 o;
      o[0] = f2bf(v.x); o[1] = f2bf(v.y); o[2] = f2bf(v.z); o[3] = f2bf(v.w);
      Xbf4[i] = o;
    }
  } else if (b < 4096) {
    // W1 [1024][512] -> W1T [512][1024]
    int o = (b - 2048) * 256 + threadIdx.x;
    int c = o >> 10, r = o & 1023;
    W1T[o] = f2bf(W1[(size_t)r * 512 + c]);
  } else {
    // W2 [512][64] -> W2T [64][512]
    int o = (b - 4096) * 256 + threadIdx.x;
    int c = o >> 9, r = o & 511;
    W2T[o] = f2bf(W2[(size_t)r * 64 + c]);
  }
}

// ================= 8-phase 256x256 GEMM for gemm2 =================
__global__ __launch_bounds__(512, 2) void gemm2_8ph(
    const unsigned short* __restrict__ A,   // Tbf [8192][8192] bf16
    const unsigned short* __restrict__ BT,  // XW1T [512][8192] bf16
    unsigned short* __restrict__ Cpart) {   // [4][8192][512] bf16 partials
  constexpr int K = 8192;
  constexpr int LDC = 512;
  constexpr int NT = 32;  // K-tiles of 64 per block (kChunk = 2048)

  __shared__ __align__(16) char lds[131072];  // [buf][A 32K | B 32K]

  const int tid = threadIdx.x;
  const int lane = tid & 63, w = tid >> 6;
  const int wr = w >> 2, wc = w & 3;          // 2 x 4 wave grid
  const int lrow = lane & 15, slot = lane >> 4;
  const int xorv = (((lrow >> 2) & 1) << 5) | (((lrow >> 3) & 1) << 6);
  const int row0 = blockIdx.x * 256;
  const int col0 = blockIdx.y * 256;
  const size_t kbeg = (size_t)blockIdx.z * 2048;

  f32x4 acc[8][4];
#pragma unroll
  for (int m = 0; m < 8; ++m)
#pragma unroll
    for (int n = 0; n < 4; ++n) acc[m][n] = (f32x4){0.f, 0.f, 0.f, 0.f};
  bf16x8 a[4][2], b[4][2];

  auto STAGE_A = [&](int buf, int h, int tk) {
    if (tk >= NT) return;
    const size_t kabs = kbeg + (size_t)tk * 64;
    char* dst = lds + buf * 65536;
#pragma unroll
    for (int j = 0; j < 2; ++j) {
      int L = h * 16384 + (j * 512 + tid) * 16;
      int y = L ^ ((L & 0x600) >> 4);
      int lam = y >> 7, cb = y & 127;
      int R = ((lam >> 6) & 1) * 128 + (lam >> 7) * 64 + (lam & 63);
      gload16((const char*)A + ((size_t)(row0 + R) * K + kabs) * 2 + cb, dst + L);
    }
  };
  auto STAGE_B = [&](int buf, int h, int tk) {
    if (tk >= NT) return;
    const size_t kabs = kbeg + (size_t)tk * 64;
    char* dst = lds + buf * 65536 + 32768;
#pragma unroll
    for (int j = 0; j < 2; ++j) {
      int L = h * 16384 + (j * 512 + tid) * 16;
      int y = L ^ ((L & 0x600) >> 4);
      int lam = y >> 7, cb = y & 127;
      int R = ((lam >> 5) & 3) * 64 + (lam >> 7) * 32 + (lam & 31);
      gload16((const char*)BT + ((size_t)(col0 + R) * K + kabs) * 2 + cb, dst + L);
    }
  };
  auto LDA = [&](int buf, int mh) {
    const char* base = lds + buf * 65536;
#pragma unroll
    for (int mm = 0; mm < 4; ++mm)
#pragma unroll
      for (int ks = 0; ks < 2; ++ks) {
        int lin = mh * 16384 + wr * 8192 + mm * 2048 + lrow * 128 + ks * 64 + slot * 16;
        a[mm][ks] = *(const bf16x8*)(base + (lin ^ xorv));
      }
  };
  auto LDB = [&](int buf, int nh) {
    const char* base = lds + buf * 65536 + 32768;
#pragma unroll
    for (int nn = 0; nn < 2; ++nn)
#pragma unroll
      for (int ks = 0; ks < 2; ++ks) {
        int lin = nh * 16384 + wc * 4096 + nn * 2048 + lrow * 128 + ks * 64 + slot * 16;
        b[nh * 2 + nn][ks] = *(const bf16x8*)(base + (lin ^ xorv));
      }
  };
  auto MMA = [&](int mh, int nh) {
    __builtin_amdgcn_s_setprio(1);
#pragma unroll
    for (int mm = 0; mm < 4; ++mm)
#pragma unroll
      for (int nn = 0; nn < 2; ++nn)
#pragma unroll
        for (int ks = 0; ks < 2; ++ks)
          acc[mh * 4 + mm][nh * 2 + nn] = __builtin_amdgcn_mfma_f32_16x16x32_bf16(
              a[mm][ks], b[nh * 2 + nn][ks], acc[mh * 4 + mm][nh * 2 + nn], 0, 0, 0);
    __builtin_amdgcn_s_setprio(0);
  };

  // prologue: tile0 fully + tile1 {A0,B0,B1}; vmcnt(6) leaves tile1's 3 newest
  STAGE_A(0, 0, 0); STAGE_B(0, 0, 0); STAGE_B(0, 1, 0); STAGE_A(0, 1, 0);
  STAGE_A(1, 0, 1); STAGE_B(1, 0, 1); STAGE_B(1, 1, 1);
  WVM6(); SBAR();

  for (int it = 0; it < NT / 2; ++it) {
    const int t = 2 * it;
    LDA(0, 0); LDB(0, 0);
    STAGE_A(1, 1, t + 1);
    SBAR(); WLG0();
    MMA(0, 0);
    SBAR();
    LDB(0, 1);
    STAGE_A(0, 0, t + 2);
    SBAR(); WLG0();
    MMA(0, 1);
    SBAR();
    LDA(0, 1);
    STAGE_B(0, 0, t + 2);
    SBAR(); WLG0();
    MMA(1, 1);
    SBAR();
    STAGE_B(0, 1, t + 2);
    WVM6();
    SBAR();
    MMA(1, 0);
    SBAR();
    LDA(1, 0); LDB(1, 0);
    STAGE_A(0, 1, t + 2);
    SBAR(); WLG0();
    MMA(0, 0);
    SBAR();
    LDB(1, 1);
    STAGE_A(1, 0, t + 3);
    SBAR(); WLG0();
    MMA(0, 1);
    SBAR();
    LDA(1, 1);
    STAGE_B(1, 0, t + 3);
    SBAR(); WLG0();
    MMA(1, 1);
    SBAR();
    STAGE_B(1, 1, t + 3);
    WVM6();
    SBAR();
    MMA(1, 0);
    SBAR();
  }

  unsigned short* Cb = Cpart + (size_t)blockIdx.z * 8192 * LDC;
  const int r0 = row0 + wr * 128, c0 = col0 + wc * 64;
#pragma unroll
  for (int m = 0; m < 8; ++m)
#pragma unroll
    for (int n = 0; n < 4; ++n)
#pragma unroll
      for (int j = 0; j < 4; ++j) {
        int row = r0 + m * 16 + (lane >> 4) * 4 + j;
        int col = c0 + n * 16 + lrow;
        Cb[(size_t)row * LDC + col] = f2bf(acc[m][n][j]);
      }
}

// ---------- tiled MFMA GEMM: C[M,N] = A[M,K] @ B[K,N], BT given as [N][K] ----------
// EPI: 1 = bf16 out + relu; 2 = f32 partial (split-K); 3 = bf16 out, (acc+bias[row])*cs[col];
//      4 = bf16 partial (split-K)
template <int BM, int BN, int EPI>
__global__ __launch_bounds__(256) void gemm_bt(
    const unsigned short* __restrict__ A,   // [M][K] bf16 row-major
    const unsigned short* __restrict__ BT,  // [N][K] bf16 row-major
    void* __restrict__ C,
    const float* __restrict__ bias,
    const float* __restrict__ cs,
    int M, int N, int K, int kChunk, int ldc) {
  constexpr int WTM = BM / 2, WTN = BN / 2;
  constexpr int MR = WTM / 16, NR = WTN / 16;
  constexpr int AIT = BM * 4 / 256;
  constexpr int BIT = BN * 4 / 256;

  __shared__ unsigned short As[BM * 32];
  __shared__ unsigned short Bs[BN * 32];

  const int t = threadIdx.x;
  const int lane = t & 63, wave = t >> 6;
  const int wr = wave >> 1, wc = wave & 1;
  const int bm = blockIdx.x, bn = blockIdx.y, bz = blockIdx.z;
  const int row0 = bm * BM, col0 = bn * BN;
  const int kbeg = bz * kChunk, kend = kbeg + kChunk;
  const int lrow = lane & 15;
  const int lk = (lane >> 4) * 8;

  f32x4 acc[MR][NR];
#pragma unroll
  for (int m = 0; m < MR; ++m)
#pragma unroll
    for (int n = 0; n < NR; ++n) acc[m][n] = (f32x4){0.f, 0.f, 0.f, 0.f};

  for (int k0 = kbeg; k0 < kend; k0 += 32) {
#pragma unroll
    for (int i = 0; i < AIT; ++i) {
      int flat = i * 256 + t;
      int r = flat >> 2, ko = (flat & 3) * 8;
      gload16(A + (size_t)(row0 + r) * K + k0 + ko, As + (size_t)flat * 8);
    }
#pragma unroll
    for (int i = 0; i < BIT; ++i) {
      int flat = i * 256 + t;
      int r = flat >> 2, ko = (flat & 3) * 8;
      gload16(BT + (size_t)(col0 + r) * K + k0 + ko, Bs + (size_t)flat * 8);
    }
    __syncthreads();

    bf16x8 af[MR], bfr[NR];
#pragma unroll
    for (int m = 0; m < MR; ++m)
      af[m] = *(const bf16x8*)&As[(wr * WTM + m * 16 + lrow) * 32 + lk];
#pragma unroll
    for (int n = 0; n < NR; ++n)
      bfr[n] = *(const bf16x8*)&Bs[(wc * WTN + n * 16 + lrow) * 32 + lk];
#pragma unroll
    for (int m = 0; m < MR; ++m)
#pragma unroll
      for (int n = 0; n < NR; ++n)
        acc[m][n] = __builtin_amdgcn_mfma_f32_16x16x32_bf16(af[m], bfr[n], acc[m][n], 0, 0, 0);
    __syncthreads();
  }

  const int r0 = row0 + wr * WTM, c0 = col0 + wc * WTN;
  if constexpr (EPI == 2) {
    float* Cf = (float*)C + (size_t)bz * M * ldc;
#pragma unroll
    for (int m = 0; m < MR; ++m)
#pragma unroll
      for (int n = 0; n < NR; ++n)
#pragma unroll
        for (int j = 0; j < 4; ++j) {
          int row = r0 + m * 16 + (lane >> 4) * 4 + j;
          int col = c0 + n * 16 + lrow;
          Cf[(size_t)row * ldc + col] = acc[m][n][j];
        }
  } else if constexpr (EPI == 4) {
    unsigned short* Cb = (unsigned short*)C + (size_t)bz * M * ldc;
#pragma unroll
    for (int m = 0; m < MR; ++m)
#pragma unroll
      for (int n = 0; n < NR; ++n)
#pragma unroll
        for (int j = 0; j < 4; ++j) {
          int row = r0 + m * 16 + (lane >> 4) * 4 + j;
          int col = c0 + n * 16 + lrow;
          Cb[(size_t)row * ldc + col] = f2bf(acc[m][n][j]);
        }
  } else {
    unsigned short* Cb = (unsigned short*)C;
#pragma unroll
    for (int m = 0; m < MR; ++m)
#pragma unroll
      for (int n = 0; n < NR; ++n)
#pragma unroll
        for (int j = 0; j < 4; ++j) {
          int row = r0 + m * 16 + (lane >> 4) * 4 + j;
          int col = c0 + n * 16 + lrow;
          float v = acc[m][n][j];
          if constexpr (EPI == 1) v = v > 0.f ? v : 0.f;
          if constexpr (EPI == 3) v = (v + bias[row]) * cs[col];
          Cb[(size_t)row * ldc + col] = f2bf(v);
        }
  }
}

// ---------- reduce bf16 split-K partials -> relu -> bf16 ----------
__global__ __launch_bounds__(256) void reduce_relu_b16p(const u16x4* __restrict__ part,
                                                        u16x4* __restrict__ out,
                                                        int total4, int splits) {
  const int stride = gridDim.x * 256;
  for (int i = blockIdx.x * 256 + threadIdx.x; i < total4; i += stride) {
    float s0 = 0.f, s1 = 0.f, s2 = 0.f, s3 = 0.f;
    for (int z = 0; z < splits; ++z) {
      u16x4 v = part[(size_t)z * total4 + i];
      s0 += bf2f(v[0]); s1 += bf2f(v[1]); s2 += bf2f(v[2]); s3 += bf2f(v[3]);
    }
    u16x4 o;
    o[0] = f2bf(s0 > 0.f ? s0 : 0.f);
    o[1] = f2bf(s1 > 0.f ? s1 : 0.f);
    o[2] = f2bf(s2 > 0.f ? s2 : 0.f);
    o[3] = f2bf(s3 > 0.f ? s3 : 0.f);
    out[i] = o;
  }
}

// ---------- reduce gemm3 f32 partials -> (s+b2[row])*sv[col] -> bf16 ZT[64][8192] ----------
__global__ __launch_bounds__(256) void reduce_zt(const float4* __restrict__ part,
                                                 const float* __restrict__ b2,
                                                 const float* __restrict__ sv,
                                                 u16x4* __restrict__ out) {
  const int i4 = blockIdx.x * 256 + threadIdx.x;  // over 64*8192/4 = 131072
  const int row = i4 >> 11;
  const int col0 = (i4 & 2047) * 4;
  float4 s = part[i4];
#pragma unroll
  for (int z = 1; z < 4; ++z) {
    float4 v = part[(size_t)z * 131072 + i4];
    s.x += v.x; s.y += v.y; s.z += v.z; s.w += v.w;
  }
  const float b = b2[row];
  u16x4 o;
  o[0] = f2bf((s.x + b) * sv[col0 + 0]);
  o[1] = f2bf((s.y + b) * sv[col0 + 1]);
  o[2] = f2bf((s.z + b) * sv[col0 + 2]);
  o[3] = f2bf((s.w + b) * sv[col0 + 3]);
  out[i4] = o;
}

// ---------- reduce gemm4 bf16 partials -> f32 out ----------
__global__ __launch_bounds__(256) void reduce_out(const u16x4* __restrict__ part,
                                                  float4* __restrict__ out,
                                                  int total4, int splits) {
  const int i = blockIdx.x * 256 + threadIdx.x;
  if (i >= total4) return;
  float s0 = 0.f, s1 = 0.f, s2 = 0.f, s3 = 0.f;
  for (int z = 0; z < splits; ++z) {
    u16x4 v = part[(size_t)z * total4 + i];
    s0 += bf2f(v[0]); s1 += bf2f(v[1]); s2 += bf2f(v[2]); s3 += bf2f(v[3]);
  }
  out[i] = (float4){s0, s1, s2, s3};
}

// ---------- launch ----------
extern "C" void kernel_launch(void* const* d_in, const int* in_sizes, int n_in,
                              void* d_out, int out_size, void* d_ws, size_t ws_size,
                              hipStream_t stream) {
  const float* X     = (const float*)d_in[0];
  const float* tilde = (const float*)d_in[1];
  const float* W1    = (const float*)d_in[2];
  const float* b1    = (const float*)d_in[3];
  const float* W2    = (const float*)d_in[4];
  const float* b2    = (const float*)d_in[5];
  float* out = (float*)d_out;

  constexpr int N = 8192, F = 1024, H = 512, Cc = 64;

  char* ws = (char*)d_ws;
  size_t off = 0;
  auto alloc = [&](size_t bytes) {
    char* p = ws + off;
    off += (bytes + 255) & ~(size_t)255;
    return p;
  };
  // persistent region
  unsigned short* Tbf  = (unsigned short*)alloc((size_t)N * N * 2);   // 128 MB
  unsigned short* XW1T = (unsigned short*)alloc((size_t)H * N * 2);   // 8 MB
  unsigned short* hbuf = (unsigned short*)alloc((size_t)N * H * 2);   // 8 MB
  unsigned short* ZT   = (unsigned short*)alloc((size_t)Cc * N * 2);  // 1 MB
  unsigned short* W2T  = (unsigned short*)alloc((size_t)Cc * H * 2);  // 64 KB
  float* partials2 = (float*)alloc(64 * N * 4);                       // 2 MB
  float* D2 = (float*)alloc(N * 4);
  float* sv = (float*)alloc(N * 4);
  // scratch zone (serial reuse):
  //  A: [Xbf 16MB | W1T 2MB pad | partials 16MB]
  //  B: part2 bf16 32MB   C: part3 f32 8MB   D: part4 bf16 8MB
  const size_t scratch_base = off;
  unsigned short* Xbf = (unsigned short*)(ws + scratch_base);                      // 16 MB
  unsigned short* W1T = (unsigned short*)(ws + scratch_base + (size_t)N * F * 2);  // 1 MB
  float* partials = (float*)(ws + scratch_base + (size_t)N * F * 2 + 0x200000);    // 16 MB
  unsigned short* part2 = (unsigned short*)(ws + scratch_base);  // 4*8192*512*2 = 32 MB
  float* part3 = (float*)(ws + scratch_base);                    // 4*64*8192*4  = 8 MB
  unsigned short* part4 = (unsigned short*)(ws + scratch_base);  // 8*8192*64*2  = 8 MB

  const size_t need_split =
      scratch_base + (size_t)N * F * 2 + 0x200000 + (size_t)512 * N * 4;
  const bool splitk = ws_size >= need_split;

  // fused sums + tilde->bf16 (A never materialized; scale folded into epilogues)
  sums_convert<<<512, 256, 0, stream>>>(tilde, (float4*)partials, D2, (u16x4*)Tbf);
  zreduce<<<dim3(8, 64), 256, 0, stream>>>((const float4*)partials, (float4*)partials2);
  colscale_kernel<<<N / 256, 256, 0, stream>>>(partials2, D2, sv);

  // fused operand prep (X convert + W1/W2 transposes), one launch
  prep_fused<<<4224, 256, 0, stream>>>((const float4*)X, (u16x4*)Xbf, W1, W1T, W2, W2T);

  // gemm1: XW1T[H][N] = W1T[H][F] @ X^T, epi: (acc+b1[row])*s[col]
  gemm_bt<64, 128, 3><<<dim3(H / 64, N / 128, 1), 256, 0, stream>>>(
      W1T, Xbf, XW1T, b1, sv, H, N, F, F, N);

  if (splitk) {
    // gemm2: 8-phase 256x256, split-K=4, bf16 partials
    gemm2_8ph<<<dim3(N / 256, H / 256, 4), 512, 0, stream>>>(Tbf, XW1T, part2);
    reduce_relu_b16p<<<1024, 256, 0, stream>>>((const u16x4*)part2, (u16x4*)hbuf,
                                               N * H / 4, 4);
    // gemm3: ZT[C][N] = W2T[C][H] @ h^T, split-K=4, f32 partials; epi in reduce_zt
    gemm_bt<64, 128, 2><<<dim3(1, N / 128, 4), 256, 0, stream>>>(
        W2T, hbuf, part3, nullptr, nullptr, Cc, N, H, H / 4, N);
    reduce_zt<<<(Cc * N / 4) / 256, 256, 0, stream>>>((const float4*)part3, b2, sv,
                                                      (u16x4*)ZT);
    // gemm4: out[N][C] = tilde_bf @ (s*Z), split-K=8, bf16 partials
    gemm_bt<128, 64, 4><<<dim3(N / 128, 1, 8), 256, 0, stream>>>(
        Tbf, ZT, part4, nullptr, nullptr, N, Cc, N, N / 8, Cc);
    reduce_out<<<(N * Cc / 4) / 256, 256, 0, stream>>>((const u16x4*)part4, (float4*)out,
                                                       N * Cc / 4, 8);
  } else {
    gemm_bt<128, 128, 1><<<dim3(N / 128, H / 128, 1), 256, 0, stream>>>(
        Tbf, XW1T, hbuf, nullptr, nullptr, N, H, N, N, H);
    gemm_bt<64, 128, 3><<<dim3(1, N / 128, 1), 256, 0, stream>>>(
        W2T, hbuf, ZT, b2, sv, Cc, N, H, H, N);
    gemm_bt<128, 64, 4><<<dim3(N / 128, 1, 1), 256, 0, stream>>>(
        Tbf, ZT, part4, nullptr, nullptr, N, Cc, N, N, Cc);
    reduce_out<<<(N * Cc / 4) / 256, 256, 0, stream>>>((const u16x4*)part4, (float4*)out,
                                                       N * Cc / 4, 1);
  }
}

// Round 9
// 255.045 us; speedup vs baseline: 1.9385x; 1.0188x over previous
//
#include <hip/hip_runtime.h>
#include <hip/hip_bf16.h>
#include <cstdint>
#include <cstddef>

// ---------- types ----------
typedef __attribute__((ext_vector_type(8))) __bf16 bf16x8;
typedef __attribute__((ext_vector_type(4))) float f32x4;
typedef __attribute__((ext_vector_type(4))) unsigned short u16x4;
typedef __attribute__((ext_vector_type(8))) unsigned short u16x8;

#define DEVINL static __device__ __forceinline__

DEVINL unsigned short f2bf(float x) {
  union { float f; unsigned u; } un; un.f = x;
  unsigned r = un.u + 0x7fffu + ((un.u >> 16) & 1u);
  return (unsigned short)(r >> 16);
}

DEVINL float bf2f(unsigned short b) {
  union { unsigned u; float f; } un; un.u = ((unsigned)b) << 16;
  return un.f;
}

DEVINL void gload16(const void* g, void* l) {
  __builtin_amdgcn_global_load_lds(
      (__attribute__((address_space(1))) void*)(void*)(uintptr_t)(const void*)g,
      (__attribute__((address_space(3))) void*)l, 16, 0, 0);
}

#define SBAR() asm volatile("s_barrier" ::: "memory")
#define WLG0() asm volatile("s_waitcnt lgkmcnt(0)" ::: "memory")
#define WVM6() asm volatile("s_waitcnt vmcnt(6)" ::: "memory")

// ---------- fused: sums of tilde + convert tilde -> bf16. NO ATOMICS. ----------
__global__ __launch_bounds__(256, 2) void sums_convert(const float* __restrict__ tilde,
                                                       float4* __restrict__ partials4,
                                                       float* __restrict__ D2,
                                                       u16x4* __restrict__ Tbf) {
  const int t = threadIdx.x;
  float4 ca[8];
#pragma unroll
  for (int i = 0; i < 8; ++i) ca[i] = (float4){0.f, 0.f, 0.f, 0.f};
  float rs[16];
#pragma unroll
  for (int r = 0; r < 16; ++r) rs[r] = 0.f;

  const int base_row = blockIdx.x * 16;
  for (int r = 0; r < 16; ++r) {
    const size_t rowoff = (size_t)(base_row + r) * 2048;  // float4 units
    const float4* rp = (const float4*)tilde + rowoff;
    u16x4* op = Tbf + rowoff;
#pragma unroll
    for (int i = 0; i < 8; ++i) {
      float4 v = rp[t + i * 256];
      ca[i].x += v.x; ca[i].y += v.y; ca[i].z += v.z; ca[i].w += v.w;
      rs[r] += (v.x + v.y) + (v.z + v.w);
      u16x4 o;
      o[0] = f2bf(v.x); o[1] = f2bf(v.y); o[2] = f2bf(v.z); o[3] = f2bf(v.w);
      op[t + i * 256] = o;
    }
  }
  float4* pb = partials4 + (size_t)blockIdx.x * 2048;
#pragma unroll
  for (int i = 0; i < 8; ++i) pb[t + i * 256] = ca[i];

#pragma unroll
  for (int r = 0; r < 16; ++r) {
#pragma unroll
    for (int off = 32; off > 0; off >>= 1) rs[r] += __shfl_down(rs[r], off, 64);
  }
  __shared__ float wsum[4][16];
  const int wave = t >> 6;
  if ((t & 63) == 0) {
#pragma unroll
    for (int r = 0; r < 16; ++r) wsum[wave][r] = rs[r];
  }
  __syncthreads();
  if (t < 16) D2[base_row + t] = wsum[0][t] + wsum[1][t] + wsum[2][t] + wsum[3][t];
}

// ---------- mega prep: zreduce | X->bf16 | W1^T | W2^T (one launch, all independent) ----------
__global__ __launch_bounds__(256) void prep_fused(const float4* __restrict__ partials4,
                                                  float4* __restrict__ partials2_4,
                                                  const float4* __restrict__ X4,
                                                  u16x4* __restrict__ Xbf4,
                                                  const float* __restrict__ W1,
                                                  unsigned short* __restrict__ W1T,
                                                  const float* __restrict__ W2,
                                                  unsigned short* __restrict__ W2T) {
  const int b = blockIdx.x;
  if (b < 512) {
    // zreduce: partials[512][8192] -> partials2[64][8192]
    const int bx = b & 7, by = b >> 3;
    const int c4 = bx * 256 + threadIdx.x;
    const int z0 = by * 8;
    float4 s = (float4){0.f, 0.f, 0.f, 0.f};
#pragma unroll
    for (int z = z0; z < z0 + 8; ++z) {
      float4 v = partials4[(size_t)z * 2048 + c4];
      s.x += v.x; s.y += v.y; s.z += v.z; s.w += v.w;
    }
    partials2_4[(size_t)by * 2048 + c4] = s;
  } else if (b < 2560) {
    const int n4 = 8192 * 1024 / 4;
    for (int i = (b - 512) * 256 + threadIdx.x; i < n4; i += 2048 * 256) {
      float4 v = X4[i];
      u16x4 o;
      o[0] = f2bf(v.x); o[1] = f2bf(v.y); o[2] = f2bf(v.z); o[3] = f2bf(v.w);
      Xbf4[i] = o;
    }
  } else if (b < 4608) {
    // W1 [1024][512] -> W1T [512][1024]
    int o = (b - 2560) * 256 + threadIdx.x;
    int c = o >> 10, r = o & 1023;
    W1T[o] = f2bf(W1[(size_t)r * 512 + c]);
  } else {
    // W2 [512][64] -> W2T [64][512]
    int o = (b - 4608) * 256 + threadIdx.x;
    int c = o >> 9, r = o & 511;
    W2T[o] = f2bf(W2[(size_t)r * 64 + c]);
  }
}

// ---------- sv[j] = sqrt(colsum[j] * D2[j]) ----------
__global__ __launch_bounds__(256) void colscale_kernel(const float* __restrict__ partials2,
                                                       const float* __restrict__ D2,
                                                       float* __restrict__ sv) {
  int j = blockIdx.x * 256 + threadIdx.x;
  float d1 = 0.f;
  for (int z = 0; z < 64; ++z) d1 += partials2[z * 8192 + j];
  sv[j] = sqrtf(d1 * D2[j]);
}

// ================= 8-phase 256x256 GEMM for gemm2 =================
// 1D grid, XCD-pairing decode: blocks sharing an A panel (same x,z; y=0/1)
// land on the same XCD (blockIdx % 8 equal) so the 2nd read L2-hits.
__global__ __launch_bounds__(512, 2) void gemm2_8ph(
    const unsigned short* __restrict__ A,   // Tbf [8192][8192] bf16
    const unsigned short* __restrict__ BT,  // XW1T [512][8192] bf16
    unsigned short* __restrict__ Cpart) {   // [4][8192][512] bf16 partials
  constexpr int K = 8192;
  constexpr int LDC = 512;
  constexpr int NT = 32;  // K-tiles of 64 per block (kChunk = 2048)

  __shared__ __align__(16) char lds[131072];  // [buf][A 32K | B 32K]

  const int tid = threadIdx.x;
  const int lane = tid & 63, w = tid >> 6;
  const int wr = w >> 2, wc = w & 3;          // 2 x 4 wave grid
  const int lrow = lane & 15, slot = lane >> 4;
  const int xorv = (((lrow >> 2) & 1) << 5) | (((lrow >> 3) & 1) << 6);
  // XCD-pairing bijection: i = xcd + 8*(xl + 4*(by + 2*bz))
  const int i = blockIdx.x;
  const int xcd = i & 7, sl = i >> 3;
  const int bx = xcd * 4 + (sl & 3);
  const int yz = sl >> 2;
  const int by = yz & 1, bz = yz >> 1;
  const int row0 = bx * 256;
  const int col0 = by * 256;
  const size_t kbeg = (size_t)bz * 2048;

  f32x4 acc[8][4];
#pragma unroll
  for (int m = 0; m < 8; ++m)
#pragma unroll
    for (int n = 0; n < 4; ++n) acc[m][n] = (f32x4){0.f, 0.f, 0.f, 0.f};
  bf16x8 a[4][2], b[4][2];

  auto STAGE_A = [&](int buf, int h, int tk) {
    if (tk >= NT) return;
    const size_t kabs = kbeg + (size_t)tk * 64;
    char* dst = lds + buf * 65536;
#pragma unroll
    for (int j = 0; j < 2; ++j) {
      int L = h * 16384 + (j * 512 + tid) * 16;
      int y = L ^ ((L & 0x600) >> 4);
      int lam = y >> 7, cb = y & 127;
      int R = ((lam >> 6) & 1) * 128 + (lam >> 7) * 64 + (lam & 63);
      gload16((const char*)A + ((size_t)(row0 + R) * K + kabs) * 2 + cb, dst + L);
    }
  };
  auto STAGE_B = [&](int buf, int h, int tk) {
    if (tk >= NT) return;
    const size_t kabs = kbeg + (size_t)tk * 64;
    char* dst = lds + buf * 65536 + 32768;
#pragma unroll
    for (int j = 0; j < 2; ++j) {
      int L = h * 16384 + (j * 512 + tid) * 16;
      int y = L ^ ((L & 0x600) >> 4);
      int lam = y >> 7, cb = y & 127;
      int R = ((lam >> 5) & 3) * 64 + (lam >> 7) * 32 + (lam & 31);
      gload16((const char*)BT + ((size_t)(col0 + R) * K + kabs) * 2 + cb, dst + L);
    }
  };
  auto LDA = [&](int buf, int mh) {
    const char* base = lds + buf * 65536;
#pragma unroll
    for (int mm = 0; mm < 4; ++mm)
#pragma unroll
      for (int ks = 0; ks < 2; ++ks) {
        int lin = mh * 16384 + wr * 8192 + mm * 2048 + lrow * 128 + ks * 64 + slot * 16;
        a[mm][ks] = *(const bf16x8*)(base + (lin ^ xorv));
      }
  };
  auto LDB = [&](int buf, int nh) {
    const char* base = lds + buf * 65536 + 32768;
#pragma unroll
    for (int nn = 0; nn < 2; ++nn)
#pragma unroll
      for (int ks = 0; ks < 2; ++ks) {
        int lin = nh * 16384 + wc * 4096 + nn * 2048 + lrow * 128 + ks * 64 + slot * 16;
        b[nh * 2 + nn][ks] = *(const bf16x8*)(base + (lin ^ xorv));
      }
  };
  auto MMA = [&](int mh, int nh) {
    __builtin_amdgcn_s_setprio(1);
#pragma unroll
    for (int mm = 0; mm < 4; ++mm)
#pragma unroll
      for (int nn = 0; nn < 2; ++nn)
#pragma unroll
        for (int ks = 0; ks < 2; ++ks)
          acc[mh * 4 + mm][nh * 2 + nn] = __builtin_amdgcn_mfma_f32_16x16x32_bf16(
              a[mm][ks], b[nh * 2 + nn][ks], acc[mh * 4 + mm][nh * 2 + nn], 0, 0, 0);
    __builtin_amdgcn_s_setprio(0);
  };

  // prologue: tile0 fully + tile1 {A0,B0,B1}; vmcnt(6) leaves tile1's 3 newest
  STAGE_A(0, 0, 0); STAGE_B(0, 0, 0); STAGE_B(0, 1, 0); STAGE_A(0, 1, 0);
  STAGE_A(1, 0, 1); STAGE_B(1, 0, 1); STAGE_B(1, 1, 1);
  WVM6(); SBAR();

  for (int it = 0; it < NT / 2; ++it) {
    const int t = 2 * it;
    LDA(0, 0); LDB(0, 0);
    STAGE_A(1, 1, t + 1);
    SBAR(); WLG0();
    MMA(0, 0);
    SBAR();
    LDB(0, 1);
    STAGE_A(0, 0, t + 2);
    SBAR(); WLG0();
    MMA(0, 1);
    SBAR();
    LDA(0, 1);
    STAGE_B(0, 0, t + 2);
    SBAR(); WLG0();
    MMA(1, 1);
    SBAR();
    STAGE_B(0, 1, t + 2);
    WVM6();
    SBAR();
    MMA(1, 0);
    SBAR();
    LDA(1, 0); LDB(1, 0);
    STAGE_A(0, 1, t + 2);
    SBAR(); WLG0();
    MMA(0, 0);
    SBAR();
    LDB(1, 1);
    STAGE_A(1, 0, t + 3);
    SBAR(); WLG0();
    MMA(0, 1);
    SBAR();
    LDA(1, 1);
    STAGE_B(1, 0, t + 3);
    SBAR(); WLG0();
    MMA(1, 1);
    SBAR();
    STAGE_B(1, 1, t + 3);
    WVM6();
    SBAR();
    MMA(1, 0);
    SBAR();
  }

  unsigned short* Cb = Cpart + (size_t)bz * 8192 * LDC;
  const int r0 = row0 + wr * 128, c0 = col0 + wc * 64;
#pragma unroll
  for (int m = 0; m < 8; ++m)
#pragma unroll
    for (int n = 0; n < 4; ++n)
#pragma unroll
      for (int j = 0; j < 4; ++j) {
        int row = r0 + m * 16 + (lane >> 4) * 4 + j;
        int col = c0 + n * 16 + lrow;
        Cb[(size_t)row * LDC + col] = f2bf(acc[m][n][j]);
      }
}

// ---------- gemm3 with fused partial-reduce+relu B-staging ----------
// ZT_part[z][64][8192] f32 = W2T[64][512] @ h^T, where h = relu(sum_z part2[z]).
// B (=h rows) staged by reg-summing the 4 bf16 partials: each h element is
// consumed exactly once across the grid, so the fusion duplicates no work.
__global__ __launch_bounds__(256) void gemm3_fused(
    const unsigned short* __restrict__ W2T,    // [64][512]
    const unsigned short* __restrict__ part2,  // [4][8192][512] bf16
    float* __restrict__ part3) {               // [4][64][8192] f32
  constexpr int BM = 64, BN = 128, K = 512;
  constexpr int PSTRIDE = 8192 * 512;
  __shared__ unsigned short As[BM * 32];
  __shared__ unsigned short Bs[BN * 32];

  const int t = threadIdx.x;
  const int lane = t & 63, wave = t >> 6;
  const int wr = wave >> 1, wc = wave & 1;
  const int col0 = blockIdx.y * BN;
  const int kbeg = blockIdx.z * 128, kend = kbeg + 128;
  const int lrow = lane & 15;
  const int lk = (lane >> 4) * 8;

  f32x4 acc[2][4];
#pragma unroll
  for (int m = 0; m < 2; ++m)
#pragma unroll
    for (int n = 0; n < 4; ++n) acc[m][n] = (f32x4){0.f, 0.f, 0.f, 0.f};

  for (int k0 = kbeg; k0 < kend; k0 += 32) {
    // A: one gload16 per thread
    {
      int r = t >> 2, ko = (t & 3) * 8;
      gload16(W2T + (size_t)r * K + k0 + ko, As + (size_t)t * 8);
    }
    // B: reg-staged sum+relu of 4 partials
#pragma unroll
    for (int i = 0; i < 2; ++i) {
      int flat = i * 256 + t;
      int r = flat >> 2, ko = (flat & 3) * 8;
      const size_t base = (size_t)(col0 + r) * K + k0 + ko;
      float s[8];
#pragma unroll
      for (int e = 0; e < 8; ++e) s[e] = 0.f;
#pragma unroll
      for (int z = 0; z < 4; ++z) {
        u16x8 v = *(const u16x8*)(part2 + (size_t)z * PSTRIDE + base);
#pragma unroll
        for (int e = 0; e < 8; ++e) s[e] += bf2f(v[e]);
      }
      u16x8 o;
#pragma unroll
      for (int e = 0; e < 8; ++e) o[e] = f2bf(s[e] > 0.f ? s[e] : 0.f);
      *(u16x8*)&Bs[(size_t)flat * 8] = o;
    }
    __syncthreads();

    bf16x8 af[2], bfr[4];
#pragma unroll
    for (int m = 0; m < 2; ++m)
      af[m] = *(const bf16x8*)&As[(wr * 32 + m * 16 + lrow) * 32 + lk];
#pragma unroll
    for (int n = 0; n < 4; ++n)
      bfr[n] = *(const bf16x8*)&Bs[(wc * 64 + n * 16 + lrow) * 32 + lk];
#pragma unroll
    for (int m = 0; m < 2; ++m)
#pragma unroll
      for (int n = 0; n < 4; ++n)
        acc[m][n] = __builtin_amdgcn_mfma_f32_16x16x32_bf16(af[m], bfr[n], acc[m][n], 0, 0, 0);
    __syncthreads();
  }

  float* Cf = part3 + (size_t)blockIdx.z * 64 * 8192;
  const int r0 = wr * 32, c0 = col0 + wc * 64;
#pragma unroll
  for (int m = 0; m < 2; ++m)
#pragma unroll
    for (int n = 0; n < 4; ++n)
#pragma unroll
      for (int j = 0; j < 4; ++j) {
        int row = r0 + m * 16 + (lane >> 4) * 4 + j;
        int col = c0 + n * 16 + lrow;
        Cf[(size_t)row * 8192 + col] = acc[m][n][j];
      }
}

// ---------- tiled MFMA GEMM (2-phase), EPI: 1 relu; 2 f32 part; 3 (acc+b)*cs; 4 bf16 part ----------
template <int BM, int BN, int EPI>
__global__ __launch_bounds__(256) void gemm_bt(
    const unsigned short* __restrict__ A,
    const unsigned short* __restrict__ BT,
    void* __restrict__ C,
    const float* __restrict__ bias,
    const float* __restrict__ cs,
    int M, int N, int K, int kChunk, int ldc) {
  constexpr int WTM = BM / 2, WTN = BN / 2;
  constexpr int MR = WTM / 16, NR = WTN / 16;
  constexpr int AIT = BM * 4 / 256;
  constexpr int BIT = BN * 4 / 256;

  __shared__ unsigned short As[BM * 32];
  __shared__ unsigned short Bs[BN * 32];

  const int t = threadIdx.x;
  const int lane = t & 63, wave = t >> 6;
  const int wr = wave >> 1, wc = wave & 1;
  const int bm = blockIdx.x, bn = blockIdx.y, bz = blockIdx.z;
  const int row0 = bm * BM, col0 = bn * BN;
  const int kbeg = bz * kChunk, kend = kbeg + kChunk;
  const int lrow = lane & 15;
  const int lk = (lane >> 4) * 8;

  f32x4 acc[MR][NR];
#pragma unroll
  for (int m = 0; m < MR; ++m)
#pragma unroll
    for (int n = 0; n < NR; ++n) acc[m][n] = (f32x4){0.f, 0.f, 0.f, 0.f};

  for (int k0 = kbeg; k0 < kend; k0 += 32) {
#pragma unroll
    for (int i = 0; i < AIT; ++i) {
      int flat = i * 256 + t;
      int r = flat >> 2, ko = (flat & 3) * 8;
      gload16(A + (size_t)(row0 + r) * K + k0 + ko, As + (size_t)flat * 8);
    }
#pragma unroll
    for (int i = 0; i < BIT; ++i) {
      int flat = i * 256 + t;
      int r = flat >> 2, ko = (flat & 3) * 8;
      gload16(BT + (size_t)(col0 + r) * K + k0 + ko, Bs + (size_t)flat * 8);
    }
    __syncthreads();

    bf16x8 af[MR], bfr[NR];
#pragma unroll
    for (int m = 0; m < MR; ++m)
      af[m] = *(const bf16x8*)&As[(wr * WTM + m * 16 + lrow) * 32 + lk];
#pragma unroll
    for (int n = 0; n < NR; ++n)
      bfr[n] = *(const bf16x8*)&Bs[(wc * WTN + n * 16 + lrow) * 32 + lk];
#pragma unroll
    for (int m = 0; m < MR; ++m)
#pragma unroll
      for (int n = 0; n < NR; ++n)
        acc[m][n] = __builtin_amdgcn_mfma_f32_16x16x32_bf16(af[m], bfr[n], acc[m][n], 0, 0, 0);
    __syncthreads();
  }

  const int r0 = row0 + wr * WTM, c0 = col0 + wc * WTN;
  if constexpr (EPI == 2) {
    float* Cf = (float*)C + (size_t)bz * M * ldc;
#pragma unroll
    for (int m = 0; m < MR; ++m)
#pragma unroll
      for (int n = 0; n < NR; ++n)
#pragma unroll
        for (int j = 0; j < 4; ++j) {
          int row = r0 + m * 16 + (lane >> 4) * 4 + j;
          int col = c0 + n * 16 + lrow;
          Cf[(size_t)row * ldc + col] = acc[m][n][j];
        }
  } else if constexpr (EPI == 4) {
    unsigned short* Cb = (unsigned short*)C + (size_t)bz * M * ldc;
#pragma unroll
    for (int m = 0; m < MR; ++m)
#pragma unroll
      for (int n = 0; n < NR; ++n)
#pragma unroll
        for (int j = 0; j < 4; ++j) {
          int row = r0 + m * 16 + (lane >> 4) * 4 + j;
          int col = c0 + n * 16 + lrow;
          Cb[(size_t)row * ldc + col] = f2bf(acc[m][n][j]);
        }
  } else {
    unsigned short* Cb = (unsigned short*)C;
#pragma unroll
    for (int m = 0; m < MR; ++m)
#pragma unroll
      for (int n = 0; n < NR; ++n)
#pragma unroll
        for (int j = 0; j < 4; ++j) {
          int row = r0 + m * 16 + (lane >> 4) * 4 + j;
          int col = c0 + n * 16 + lrow;
          float v = acc[m][n][j];
          if constexpr (EPI == 1) v = v > 0.f ? v : 0.f;
          if constexpr (EPI == 3) v = (v + bias[row]) * cs[col];
          Cb[(size_t)row * ldc + col] = f2bf(v);
        }
  }
}

// ---------- reduce bf16 split-K partials -> relu -> bf16 (fallback path only) ----------
__global__ __launch_bounds__(256) void reduce_relu_b16p(const u16x4* __restrict__ part,
                                                        u16x4* __restrict__ out,
                                                        int total4, int splits) {
  const int stride = gridDim.x * 256;
  for (int i = blockIdx.x * 256 + threadIdx.x; i < total4; i += stride) {
    float s0 = 0.f, s1 = 0.f, s2 = 0.f, s3 = 0.f;
    for (int z = 0; z < splits; ++z) {
      u16x4 v = part[(size_t)z * total4 + i];
      s0 += bf2f(v[0]); s1 += bf2f(v[1]); s2 += bf2f(v[2]); s3 += bf2f(v[3]);
    }
    u16x4 o;
    o[0] = f2bf(s0 > 0.f ? s0 : 0.f);
    o[1] = f2bf(s1 > 0.f ? s1 : 0.f);
    o[2] = f2bf(s2 > 0.f ? s2 : 0.f);
    o[3] = f2bf(s3 > 0.f ? s3 : 0.f);
    out[i] = o;
  }
}

// ---------- reduce gemm3 f32 partials -> (s+b2[row])*sv[col] -> bf16 ZT[64][8192] ----------
__global__ __launch_bounds__(256) void reduce_zt(const float4* __restrict__ part,
                                                 const float* __restrict__ b2,
                                                 const float* __restrict__ sv,
                                                 u16x4* __restrict__ out,
                                                 int splits) {
  const int i4 = blockIdx.x * 256 + threadIdx.x;  // over 64*8192/4 = 131072
  const int row = i4 >> 11;
  const int col0 = (i4 & 2047) * 4;
  float4 s = part[i4];
  for (int z = 1; z < splits; ++z) {
    float4 v = part[(size_t)z * 131072 + i4];
    s.x += v.x; s.y += v.y; s.z += v.z; s.w += v.w;
  }
  const float b = b2[row];
  u16x4 o;
  o[0] = f2bf((s.x + b) * sv[col0 + 0]);
  o[1] = f2bf((s.y + b) * sv[col0 + 1]);
  o[2] = f2bf((s.z + b) * sv[col0 + 2]);
  o[3] = f2bf((s.w + b) * sv[col0 + 3]);
  out[i4] = o;
}

// ---------- reduce gemm4 bf16 partials -> f32 out ----------
__global__ __launch_bounds__(256) void reduce_out(const u16x4* __restrict__ part,
                                                  float4* __restrict__ out,
                                                  int total4, int splits) {
  const int i = blockIdx.x * 256 + threadIdx.x;
  if (i >= total4) return;
  float s0 = 0.f, s1 = 0.f, s2 = 0.f, s3 = 0.f;
  for (int z = 0; z < splits; ++z) {
    u16x4 v = part[(size_t)z * total4 + i];
    s0 += bf2f(v[0]); s1 += bf2f(v[1]); s2 += bf2f(v[2]); s3 += bf2f(v[3]);
  }
  out[i] = (float4){s0, s1, s2, s3};
}

// ---------- launch ----------
extern "C" void kernel_launch(void* const* d_in, const int* in_sizes, int n_in,
                              void* d_out, int out_size, void* d_ws, size_t ws_size,
                              hipStream_t stream) {
  const float* X     = (const float*)d_in[0];
  const float* tilde = (const float*)d_in[1];
  const float* W1    = (const float*)d_in[2];
  const float* b1    = (const float*)d_in[3];
  const float* W2    = (const float*)d_in[4];
  const float* b2    = (const float*)d_in[5];
  float* out = (float*)d_out;

  constexpr int N = 8192, F = 1024, H = 512, Cc = 64;

  char* ws = (char*)d_ws;
  size_t off = 0;
  auto alloc = [&](size_t bytes) {
    char* p = ws + off;
    off += (bytes + 255) & ~(size_t)255;
    return p;
  };
  // persistent region
  unsigned short* Tbf  = (unsigned short*)alloc((size_t)N * N * 2);   // 128 MB
  unsigned short* XW1T = (unsigned short*)alloc((size_t)H * N * 2);   // 8 MB
  unsigned short* hbuf = (unsigned short*)alloc((size_t)N * H * 2);   // 8 MB (fallback)
  unsigned short* ZT   = (unsigned short*)alloc((size_t)Cc * N * 2);  // 1 MB
  unsigned short* W2T  = (unsigned short*)alloc((size_t)Cc * H * 2);  // 64 KB
  float* partials2 = (float*)alloc(64 * N * 4);                       // 2 MB
  float* D2 = (float*)alloc(N * 4);
  float* sv = (float*)alloc(N * 4);
  // scratch zone (serial reuse):
  //  A: [Xbf 16MB | W1T 2MB pad | partials 16MB]
  //  B: part2 bf16 32MB @base     C: part3 f32 8MB @base+32MB (part2 still live!)
  //  D: part4 bf16 8MB @base
  const size_t scratch_base = off;
  unsigned short* Xbf = (unsigned short*)(ws + scratch_base);                      // 16 MB
  unsigned short* W1T = (unsigned short*)(ws + scratch_base + (size_t)N * F * 2);  // 1 MB
  float* partials = (float*)(ws + scratch_base + (size_t)N * F * 2 + 0x200000);    // 16 MB
  unsigned short* part2 = (unsigned short*)(ws + scratch_base);                  // 32 MB
  float* part3 = (float*)(ws + scratch_base + (size_t)4 * N * H * 2);            // 8 MB
  unsigned short* part4 = (unsigned short*)(ws + scratch_base);                  // 8 MB

  const size_t scratch_need = (size_t)4 * N * H * 2 + (size_t)4 * Cc * N * 4;  // 40 MB
  const bool splitk = ws_size >= scratch_base + scratch_need;

  // fused sums + tilde->bf16
  sums_convert<<<512, 256, 0, stream>>>(tilde, (float4*)partials, D2, (u16x4*)Tbf);
  // mega prep: zreduce + X convert + W transposes
  prep_fused<<<4736, 256, 0, stream>>>((const float4*)partials, (float4*)partials2,
                                       (const float4*)X, (u16x4*)Xbf, W1, W1T, W2, W2T);
  colscale_kernel<<<N / 256, 256, 0, stream>>>(partials2, D2, sv);

  // gemm1: XW1T[H][N] = W1T[H][F] @ X^T, epi: (acc+b1[row])*s[col]
  gemm_bt<64, 128, 3><<<dim3(H / 64, N / 128, 1), 256, 0, stream>>>(
      W1T, Xbf, XW1T, b1, sv, H, N, F, F, N);

  if (splitk) {
    // gemm2: 8-phase 256x256, split-K=4, bf16 partials, XCD-paired 1D grid
    gemm2_8ph<<<256, 512, 0, stream>>>(Tbf, XW1T, part2);
    // gemm3 with fused partial-reduce+relu B staging (hbuf eliminated)
    gemm3_fused<<<dim3(1, N / 128, 4), 256, 0, stream>>>(W2T, part2, part3);
    reduce_zt<<<(Cc * N / 4) / 256, 256, 0, stream>>>((const float4*)part3, b2, sv,
                                                      (u16x4*)ZT, 4);
    // gemm4: out[N][C] = tilde_bf @ (s*Z), split-K=8, bf16 partials
    gemm_bt<128, 64, 4><<<dim3(N / 128, 1, 8), 256, 0, stream>>>(
        Tbf, ZT, part4, nullptr, nullptr, N, Cc, N, N / 8, Cc);
    reduce_out<<<(N * Cc / 4) / 256, 256, 0, stream>>>((const u16x4*)part4, (float4*)out,
                                                       N * Cc / 4, 8);
  } else {
    gemm_bt<128, 128, 1><<<dim3(N / 128, H / 128, 1), 256, 0, stream>>>(
        Tbf, XW1T, hbuf, nullptr, nullptr, N, H, N, N, H);
    gemm_bt<64, 128, 2><<<dim3(1, N / 128, 1), 256, 0, stream>>>(
        W2T, hbuf, part3, nullptr, nullptr, Cc, N, H, H, N);
    reduce_zt<<<(Cc * N / 4) / 256, 256, 0, stream>>>((const float4*)part3, b2, sv,
                                                      (u16x4*)ZT, 1);
    gemm_bt<128, 64, 4><<<dim3(N / 128, 1, 1), 256, 0, stream>>>(
        Tbf, ZT, part4, nullptr, nullptr, N, Cc, N, N, Cc);
    reduce_out<<<(N * Cc / 4) / 256, 256, 0, stream>>>((const u16x4*)part4, (float4*)out,
                                                       N * Cc / 4, 1);
  }
}